// Round 6
// baseline (641.149 us; speedup 1.0000x reference)
//
#include <hip/hip_runtime.h>
#include <math.h>

// CSR build via contention-free radix grouping.
// R2/R4 evidence: random 4B scatter = 96-105MB WRITE_SIZE for 6.4MB payload
// (random-line writeback ceiling ~750GB/s, 135us). R3 evidence: 1.6M global
// atomics on 782 cursors = 376us (contention). This path has NO global
// atomics and all global writes are sequential runs.

#define BKT_SHIFT 7
#define BKT_NODES 128
#define BKT_CAP 4096   // LDS staging cap; overflow -> direct-write fallback
#define EPB 16384      // edges per block in hist/group passes (64 iters x 256)

// ---------------- phase A: per-(bucket,block) histogram ----------------
__global__ __launch_bounds__(256) void block_hist_kernel(
    const int* __restrict__ dst, int* __restrict__ hist, int E, int NBKT, int NBLK) {
  __shared__ int lh[1024];  // >= NBKT
  const int t = threadIdx.x;
  const int blk = blockIdx.x;
  for (int k = t; k < NBKT; k += 256) lh[k] = 0;
  __syncthreads();
  const int e0 = blk * EPB;
  const int e1 = min(e0 + EPB, E);
  for (int e = e0 + t; e < e1; e += 256) atomicAdd(&lh[dst[e] >> BKT_SHIFT], 1);
  __syncthreads();
  for (int k = t; k < NBKT; k += 256) hist[k * NBLK + blk] = lh[k];
}

// ---------------- phase B: scan (single block, 1024 thr) ----------------
// bbase[k] = global base of bucket k (exclusive prefix of bucket totals);
// ebase[k*NBLK+blk] = base of block blk's run within bucket k. bbase[NBKT]=E.
__global__ __launch_bounds__(1024) void scan_kernel(
    const int* __restrict__ hist, int* __restrict__ bbase, int* __restrict__ ebase,
    int E, int NBKT, int NBLK) {
  __shared__ int sh[1024];
  const int t = threadIdx.x;
  int total = 0;
  if (t < NBKT) {
    const int* row = hist + (long)t * NBLK;
    for (int i = 0; i < NBLK; ++i) total += row[i];
  }
  sh[t] = total;
  __syncthreads();
  for (int s = 1; s < 1024; s <<= 1) {
    int add = (t >= s) ? sh[t - s] : 0;
    __syncthreads();
    sh[t] += add;
    __syncthreads();
  }
  if (t < NBKT) {
    int ex = sh[t] - total;
    bbase[t] = ex;
    const int* row = hist + (long)t * NBLK;
    int* erow = ebase + (long)t * NBLK;
    int run = ex;
    for (int i = 0; i < NBLK; ++i) { erow[i] = run; run += row[i]; }
  }
  if (t == 0) bbase[NBKT] = E;
}

// ---------------- phase C: group edges by bucket (sequential runs) --------
__global__ __launch_bounds__(256) void group_kernel(
    const int* __restrict__ src, const int* __restrict__ dst,
    const int* __restrict__ ebase, unsigned int* __restrict__ grouped,
    int E, int NBKT, int NBLK) {
  __shared__ int lcur[1024];
  const int t = threadIdx.x;
  const int blk = blockIdx.x;
  for (int k = t; k < NBKT; k += 256) lcur[k] = ebase[(long)k * NBLK + blk];
  __syncthreads();
  const int e0 = blk * EPB;
  const int e1 = min(e0 + EPB, E);
  for (int e = e0 + t; e < e1; e += 256) {
    int d = dst[e];
    int b = d >> BKT_SHIFT;
    int pos = atomicAdd(&lcur[b], 1);
    grouped[pos] = ((unsigned int)(d & (BKT_NODES - 1)) << 17) | (unsigned int)src[e];
  }
}

// ---------------- phase D: per-bucket CSR finalize + ends + dis ----------
__global__ __launch_bounds__(256) void bucket_build_kernel(
    const unsigned int* __restrict__ grouped, const int* __restrict__ bbase,
    int* __restrict__ csr_src, int* __restrict__ ends, float* __restrict__ dis, int N) {
  __shared__ int lcnt[BKT_NODES];
  __shared__ int lsum[BKT_NODES];
  __shared__ int lcur[BKT_NODES];
  __shared__ int stage[BKT_CAP];
  const int b = blockIdx.x;
  const int t = threadIdx.x;
  const int node0 = b << BKT_SHIFT;
  const int nn = min(BKT_NODES, N - node0);
  const int base = bbase[b];
  const int m = bbase[b + 1] - base;

  if (t < BKT_NODES) lcnt[t] = 0;
  __syncthreads();
  for (int i = t; i < m; i += 256) atomicAdd(&lcnt[grouped[base + i] >> 17], 1);
  __syncthreads();
  if (t < BKT_NODES) lsum[t] = lcnt[t];
  __syncthreads();
  for (int s = 1; s < BKT_NODES; s <<= 1) {
    int add = 0;
    if (t < BKT_NODES && t >= s) add = lsum[t - s];
    __syncthreads();
    if (t < BKT_NODES) lsum[t] += add;
    __syncthreads();
  }
  if (t < nn) {
    ends[node0 + t] = base + lsum[t];                      // global inclusive end
    dis[node0 + t] = 1.0f / sqrtf((float)(lcnt[t] + 1));   // +1 self loop
    lcur[t] = lsum[t] - lcnt[t];                           // local exclusive cursor
  }
  __syncthreads();
  if (m <= BKT_CAP) {
    for (int i = t; i < m; i += 256) {
      unsigned int v = grouped[base + i];
      int p = atomicAdd(&lcur[v >> 17], 1);
      stage[p] = (int)(v & 0x1FFFFu);
    }
    __syncthreads();
    for (int i = t; i < m; i += 256) csr_src[base + i] = stage[i];
  } else {  // statistically never; correctness fallback
    for (int i = t; i < m; i += 256) {
      unsigned int v = grouped[base + i];
      int p = atomicAdd(&lcur[v >> 17], 1);
      csr_src[base + p] = (int)(v & 0x1FFFFu);
    }
  }
}

// ---------------- GEMM: C[N,64] = (H[N,K] @ W[K,64]) * dis[row] ----------------

template <int K>
__global__ __launch_bounds__(256) void gemm_kernel(const float* __restrict__ H,
                                                   const float* __restrict__ W,
                                                   const float* __restrict__ dis,
                                                   float* __restrict__ C, int N) {
  __shared__ float Hs[64][65];
  __shared__ float Ws[K][64];
  const int t = threadIdx.x;
  const int rowBase = blockIdx.x * 64;
  for (int i = t; i < K * 64; i += 256) Ws[i >> 6][i & 63] = W[i];

  const int cg = t & 7, pr = t >> 3;
  const int c0 = cg * 8, r0 = pr * 2;
  float acc0[8] = {0.f, 0.f, 0.f, 0.f, 0.f, 0.f, 0.f, 0.f};
  float acc1[8] = {0.f, 0.f, 0.f, 0.f, 0.f, 0.f, 0.f, 0.f};

  for (int k0 = 0; k0 < K; k0 += 64) {
    __syncthreads();
    for (int i = t; i < 64 * 64; i += 256) {
      int r = i >> 6, kk = i & 63;
      int gr = rowBase + r;
      Hs[r][kk] = (gr < N) ? H[(long)gr * K + k0 + kk] : 0.f;
    }
    __syncthreads();
#pragma unroll 8
    for (int kk = 0; kk < 64; ++kk) {
      float h0 = Hs[r0][kk];
      float h1 = Hs[r0 + 1][kk];
      const float4 w0 = *reinterpret_cast<const float4*>(&Ws[k0 + kk][c0]);
      const float4 w1 = *reinterpret_cast<const float4*>(&Ws[k0 + kk][c0 + 4]);
      acc0[0] += h0 * w0.x; acc0[1] += h0 * w0.y; acc0[2] += h0 * w0.z; acc0[3] += h0 * w0.w;
      acc0[4] += h0 * w1.x; acc0[5] += h0 * w1.y; acc0[6] += h0 * w1.z; acc0[7] += h0 * w1.w;
      acc1[0] += h1 * w0.x; acc1[1] += h1 * w0.y; acc1[2] += h1 * w0.z; acc1[3] += h1 * w0.w;
      acc1[4] += h1 * w1.x; acc1[5] += h1 * w1.y; acc1[6] += h1 * w1.z; acc1[7] += h1 * w1.w;
    }
  }
  int gr0 = rowBase + r0;
  if (gr0 < N) {
    float s = dis[gr0];
    float4* o = reinterpret_cast<float4*>(&C[(long)gr0 * 64 + c0]);
    o[0] = make_float4(acc0[0] * s, acc0[1] * s, acc0[2] * s, acc0[3] * s);
    o[1] = make_float4(acc0[4] * s, acc0[5] * s, acc0[6] * s, acc0[7] * s);
  }
  if (gr0 + 1 < N) {
    float s = dis[gr0 + 1];
    float4* o = reinterpret_cast<float4*>(&C[(long)(gr0 + 1) * 64 + c0]);
    o[0] = make_float4(acc1[0] * s, acc1[1] * s, acc1[2] * s, acc1[3] * s);
    o[1] = make_float4(acc1[4] * s, acc1[5] * s, acc1[6] * s, acc1[7] * s);
  }
}

// ---------------- aggregation (CSR, float4 lanes, 4 edge sub-slots) ------
// Ts rows pre-scaled by dis[src]. out[d] = relu(dis[d]*(Ts[d] + sum Ts[s]) + b)

__global__ __launch_bounds__(256) void aggregate_kernel(
    const float* __restrict__ Ts, const int* __restrict__ csr_src,
    const int* __restrict__ ends, const float* __restrict__ dis,
    const float* __restrict__ bias, float* __restrict__ O, int N) {
  int gid = blockIdx.x * 256 + threadIdx.x;
  int d = gid >> 6;
  if (d >= N) return;
  int lane = threadIdx.x & 63;
  int q = lane >> 4;
  int c = lane & 15;
  int beg = (d == 0) ? 0 : ends[d - 1];
  int m = ends[d] - beg;
  const float4* Tv = (const float4*)Ts;
  const int* sl = csr_src + beg;

  float4 a = make_float4(0.f, 0.f, 0.f, 0.f);
  float4 a2 = make_float4(0.f, 0.f, 0.f, 0.f);
  if (q == 0) a = Tv[(long)d * 16 + c];  // self loop (pre-scaled by dis[d])

  int i = q;
  for (; i + 4 < m; i += 8) {
    int s0 = sl[i];
    int s1 = sl[i + 4];
    float4 r0 = Tv[(long)s0 * 16 + c];
    float4 r1 = Tv[(long)s1 * 16 + c];
    a.x += r0.x; a.y += r0.y; a.z += r0.z; a.w += r0.w;
    a2.x += r1.x; a2.y += r1.y; a2.z += r1.z; a2.w += r1.w;
  }
  if (i < m) {
    float4 r = Tv[(long)sl[i] * 16 + c];
    a.x += r.x; a.y += r.y; a.z += r.z; a.w += r.w;
  }
  a.x += a2.x; a.y += a2.y; a.z += a2.z; a.w += a2.w;

  a.x += __shfl_xor(a.x, 16, 64); a.y += __shfl_xor(a.y, 16, 64);
  a.z += __shfl_xor(a.z, 16, 64); a.w += __shfl_xor(a.w, 16, 64);
  a.x += __shfl_xor(a.x, 32, 64); a.y += __shfl_xor(a.y, 32, 64);
  a.z += __shfl_xor(a.z, 32, 64); a.w += __shfl_xor(a.w, 32, 64);

  if (q == 0) {
    float dd = dis[d];
    float4 b4 = ((const float4*)bias)[c];
    float4 o;
    o.x = fmaxf(a.x * dd + b4.x, 0.f);
    o.y = fmaxf(a.y * dd + b4.y, 0.f);
    o.z = fmaxf(a.z * dd + b4.z, 0.f);
    o.w = fmaxf(a.w * dd + b4.w, 0.f);
    ((float4*)O)[(long)d * 16 + c] = o;
  }
}

// ---------------- pooling ----------------

__global__ void logits_kernel(const float* __restrict__ clo, const float* __restrict__ Wc,
                              const float* __restrict__ bc, float* __restrict__ lb, int N) {
  int i = blockIdx.x * blockDim.x + threadIdx.x;
  if (i >= N) return;
  float s = bc[0];
#pragma unroll
  for (int k = 0; k < 8; ++k) s += clo[(long)i * 8 + k] * Wc[k];
  lb[i] = s;
}

__global__ __launch_bounds__(256) void pool_kernel(
    const float* __restrict__ h3, const float* __restrict__ lb,
    const int* __restrict__ batch, const float* __restrict__ Wa1,
    const float* __restrict__ ba1, const float* __restrict__ Wa2,
    const float* __restrict__ ba2, float* __restrict__ out, int N) {
  __shared__ int sLo, sHi;
  __shared__ float red[256];
  __shared__ float Vs[4][64];
  __shared__ float sse[4];
  __shared__ float gv[64];
  __shared__ float am[16];
  const int g = blockIdx.x;
  const int t = threadIdx.x;
  if (t == 0) {
    int lo = 0, hi = N;
    while (lo < hi) { int mid = (lo + hi) >> 1; if (batch[mid] < g) lo = mid + 1; else hi = mid; }
    sLo = lo;
    lo = 0; hi = N;
    while (lo < hi) { int mid = (lo + hi) >> 1; if (batch[mid] < g + 1) lo = mid + 1; else hi = mid; }
    sHi = lo;
  }
  __syncthreads();
  const int lo = sLo, hi = sHi;

  float lm = -1e30f;
  for (int i = lo + t; i < hi; i += 256) lm = fmaxf(lm, lb[i]);
  red[t] = lm;
  __syncthreads();
  for (int s = 128; s > 0; s >>= 1) {
    if (t < s) red[t] = fmaxf(red[t], red[t + s]);
    __syncthreads();
  }
  const float m = red[0];

  const int f = t & 63, sub = t >> 6;
  float vacc = 0.f, seacc = 0.f;
  for (int i = lo + sub; i < hi; i += 4) {
    float e = expf(lb[i] - m);
    seacc += e;
    vacc += e * h3[(long)i * 64 + f];
  }
  Vs[sub][f] = vacc;
  if (f == 0) sse[sub] = seacc;
  __syncthreads();
  if (t < 64) {
    float se = sse[0] + sse[1] + sse[2] + sse[3];
    float v = Vs[0][f] + Vs[1][f] + Vs[2][f] + Vs[3][f];
    gv[f] = (se > 0.f) ? v / se : 0.f;
  }
  __syncthreads();
  if (t < 16) {
    float a = ba1[t];
#pragma unroll
    for (int k2 = 0; k2 < 64; ++k2) a += gv[k2] * Wa1[k2 * 16 + t];
    am[t] = a > 0.f ? a : 0.f;
  }
  __syncthreads();
  if (t == 0) {
    float o = ba2[0];
#pragma unroll
    for (int j = 0; j < 16; ++j) o += am[j] * Wa2[j];
    out[g] = o;
  }
}

// ---------------- launcher ----------------

extern "C" void kernel_launch(void* const* d_in, const int* in_sizes, int n_in,
                              void* d_out, int out_size, void* d_ws, size_t ws_size,
                              hipStream_t stream) {
  const float* x   = (const float*)d_in[0];
  const float* clo = (const float*)d_in[1];
  const float* W1  = (const float*)d_in[2];
  const float* b1  = (const float*)d_in[3];
  const float* W2  = (const float*)d_in[4];
  const float* b2  = (const float*)d_in[5];
  const float* W3  = (const float*)d_in[6];
  const float* b3  = (const float*)d_in[7];
  const float* Wc  = (const float*)d_in[8];
  const float* bc  = (const float*)d_in[9];
  const float* Wa1 = (const float*)d_in[10];
  const float* ba1 = (const float*)d_in[11];
  const float* Wa2 = (const float*)d_in[12];
  const float* ba2 = (const float*)d_in[13];
  const int* edge  = (const int*)d_in[14];
  const int* batch = (const int*)d_in[15];
  float* out = (float*)d_out;

  const int N = in_sizes[15];        // 100000
  const int E = in_sizes[14] / 2;    // 1600000
  const int G = out_size;            // 256
  const int NBKT = (N + BKT_NODES - 1) >> BKT_SHIFT;  // 782 (<=1024)
  const int NBLK = (E + EPB - 1) / EPB;               // 98

  const int* src = edge;
  const int* dst = edge + E;

  char* p = (char*)d_ws;
  auto alloc = [&](size_t bytes) -> char* {
    char* r = p;
    p += (bytes + 255) & ~(size_t)255;
    return r;
  };
  float* bufA           = (float*)alloc((size_t)N * 64 * sizeof(float));
  float* bufB           = (float*)alloc((size_t)N * 64 * sizeof(float));
  int*   csr_src        = (int*)  alloc((size_t)E * sizeof(int));
  unsigned int* grouped = (unsigned int*)alloc((size_t)E * sizeof(unsigned int));
  int*   hist           = (int*)  alloc((size_t)NBKT * NBLK * sizeof(int));
  int*   ebase          = (int*)  alloc((size_t)NBKT * NBLK * sizeof(int));
  int*   bbase          = (int*)  alloc((size_t)(NBKT + 1) * sizeof(int));
  int*   ends           = (int*)  alloc((size_t)N * sizeof(int));
  float* dis            = (float*)alloc((size_t)N * sizeof(float));
  float* lb             = (float*)alloc((size_t)N * sizeof(float));
  (void)ws_size; (void)n_in;

  block_hist_kernel<<<NBLK, 256, 0, stream>>>(dst, hist, E, NBKT, NBLK);
  scan_kernel<<<1, 1024, 0, stream>>>(hist, bbase, ebase, E, NBKT, NBLK);
  group_kernel<<<NBLK, 256, 0, stream>>>(src, dst, ebase, grouped, E, NBKT, NBLK);
  bucket_build_kernel<<<NBKT, 256, 0, stream>>>(grouped, bbase, csr_src, ends, dis, N);

  const int gN = (N + 255) / 256;
  const int gGemm = (N + 63) / 64;
  const int gAgg  = (N * 64 + 255) / 256;

  gemm_kernel<128><<<gGemm, 256, 0, stream>>>(x, W1, dis, bufA, N);
  aggregate_kernel<<<gAgg, 256, 0, stream>>>(bufA, csr_src, ends, dis, b1, bufB, N);
  gemm_kernel<64><<<gGemm, 256, 0, stream>>>(bufB, W2, dis, bufA, N);
  aggregate_kernel<<<gAgg, 256, 0, stream>>>(bufA, csr_src, ends, dis, b2, bufB, N);
  gemm_kernel<64><<<gGemm, 256, 0, stream>>>(bufB, W3, dis, bufA, N);
  aggregate_kernel<<<gAgg, 256, 0, stream>>>(bufA, csr_src, ends, dis, b3, bufB, N);

  logits_kernel<<<gN, 256, 0, stream>>>(clo, Wc, bc, lb, N);
  pool_kernel<<<G, 256, 0, stream>>>(bufB, lb, batch, Wa1, ba1, Wa2, ba2, out, N);
}

// Round 7
// 517.215 us; speedup vs baseline: 1.2396x; 1.2396x over previous
//
#include <hip/hip_runtime.h>
#include <math.h>

// CSR build via contention-free radix grouping.
// R2/R4: random 4B scatter = 96-105MB WRITE_SIZE for 6.4MB payload (random-line
// writeback ceiling, 135us). R3: 1.6M global atomics on 782 cursors = 376us.
// R6: single-block serial scan = 130us @ 0.14% occupancy. This version: no
// global atomics, sequential-run writes, and a grid-parallel 2-level scan.

#define BKT_SHIFT 7
#define BKT_NODES 128
#define BKT_CAP 4096   // LDS staging cap; overflow -> direct-write fallback
#define EPB 16384      // edges per block in hist/group passes (64 iters x 256)

// ---------------- phase A: per-(bucket,block) histogram ----------------
__global__ __launch_bounds__(256) void block_hist_kernel(
    const int* __restrict__ dst, int* __restrict__ hist, int E, int NBKT, int NBLK) {
  __shared__ int lh[1024];  // >= NBKT
  const int t = threadIdx.x;
  const int blk = blockIdx.x;
  for (int k = t; k < NBKT; k += 256) lh[k] = 0;
  __syncthreads();
  const int e0 = blk * EPB;
  const int e1 = min(e0 + EPB, E);
  for (int e = e0 + t; e < e1; e += 256) atomicAdd(&lh[dst[e] >> BKT_SHIFT], 1);
  __syncthreads();
  for (int k = t; k < NBKT; k += 256) hist[k * NBLK + blk] = lh[k];
}

// ---------------- phase B1: per-bucket row scan (grid-parallel) ----------
// ebase[k*NBLK+blk] = exclusive prefix of hist row k (row-relative);
// btot[k] = bucket total.
__global__ __launch_bounds__(128) void row_scan_kernel(
    const int* __restrict__ hist, int* __restrict__ ebase, int* __restrict__ btot,
    int NBLK) {
  __shared__ int sh[128];
  const int k = blockIdx.x;
  const int t = threadIdx.x;
  int v = (t < NBLK) ? hist[(long)k * NBLK + t] : 0;
  sh[t] = v;
  __syncthreads();
  for (int s = 1; s < 128; s <<= 1) {
    int add = (t >= s) ? sh[t - s] : 0;
    __syncthreads();
    sh[t] += add;
    __syncthreads();
  }
  if (t < NBLK) ebase[(long)k * NBLK + t] = sh[t] - v;  // row-local exclusive
  if (t == 127) btot[k] = sh[127];
}

// ---------------- phase B2: scan bucket totals (single block, LDS-only) --
__global__ __launch_bounds__(1024) void bucket_scan_kernel(
    const int* __restrict__ btot, int* __restrict__ bbase, int E, int NBKT) {
  __shared__ int sh[1024];
  const int t = threadIdx.x;
  int v = (t < NBKT) ? btot[t] : 0;
  sh[t] = v;
  __syncthreads();
  for (int s = 1; s < 1024; s <<= 1) {
    int add = (t >= s) ? sh[t - s] : 0;
    __syncthreads();
    sh[t] += add;
    __syncthreads();
  }
  if (t < NBKT) bbase[t] = sh[t] - v;
  if (t == 0) bbase[NBKT] = E;
}

// ---------------- phase C: group edges by bucket (sequential runs) --------
__global__ __launch_bounds__(256) void group_kernel(
    const int* __restrict__ src, const int* __restrict__ dst,
    const int* __restrict__ bbase, const int* __restrict__ ebase,
    unsigned int* __restrict__ grouped, int E, int NBKT, int NBLK) {
  __shared__ int lcur[1024];
  const int t = threadIdx.x;
  const int blk = blockIdx.x;
  for (int k = t; k < NBKT; k += 256)
    lcur[k] = bbase[k] + ebase[(long)k * NBLK + blk];
  __syncthreads();
  const int e0 = blk * EPB;
  const int e1 = min(e0 + EPB, E);
  for (int e = e0 + t; e < e1; e += 256) {
    int d = dst[e];
    int b = d >> BKT_SHIFT;
    int pos = atomicAdd(&lcur[b], 1);
    grouped[pos] = ((unsigned int)(d & (BKT_NODES - 1)) << 17) | (unsigned int)src[e];
  }
}

// ---------------- phase D: per-bucket CSR finalize + ends + dis ----------
__global__ __launch_bounds__(256) void bucket_build_kernel(
    const unsigned int* __restrict__ grouped, const int* __restrict__ bbase,
    int* __restrict__ csr_src, int* __restrict__ ends, float* __restrict__ dis, int N) {
  __shared__ int lcnt[BKT_NODES];
  __shared__ int lsum[BKT_NODES];
  __shared__ int lcur[BKT_NODES];
  __shared__ int stage[BKT_CAP];
  const int b = blockIdx.x;
  const int t = threadIdx.x;
  const int node0 = b << BKT_SHIFT;
  const int nn = min(BKT_NODES, N - node0);
  const int base = bbase[b];
  const int m = bbase[b + 1] - base;

  if (t < BKT_NODES) lcnt[t] = 0;
  __syncthreads();
  for (int i = t; i < m; i += 256) atomicAdd(&lcnt[grouped[base + i] >> 17], 1);
  __syncthreads();
  if (t < BKT_NODES) lsum[t] = lcnt[t];
  __syncthreads();
  for (int s = 1; s < BKT_NODES; s <<= 1) {
    int add = 0;
    if (t < BKT_NODES && t >= s) add = lsum[t - s];
    __syncthreads();
    if (t < BKT_NODES) lsum[t] += add;
    __syncthreads();
  }
  if (t < nn) {
    ends[node0 + t] = base + lsum[t];                      // global inclusive end
    dis[node0 + t] = 1.0f / sqrtf((float)(lcnt[t] + 1));   // +1 self loop
    lcur[t] = lsum[t] - lcnt[t];                           // local exclusive cursor
  }
  __syncthreads();
  if (m <= BKT_CAP) {
    for (int i = t; i < m; i += 256) {
      unsigned int v = grouped[base + i];
      int p = atomicAdd(&lcur[v >> 17], 1);
      stage[p] = (int)(v & 0x1FFFFu);
    }
    __syncthreads();
    for (int i = t; i < m; i += 256) csr_src[base + i] = stage[i];
  } else {  // statistically never; correctness fallback
    for (int i = t; i < m; i += 256) {
      unsigned int v = grouped[base + i];
      int p = atomicAdd(&lcur[v >> 17], 1);
      csr_src[base + p] = (int)(v & 0x1FFFFu);
    }
  }
}

// ---------------- GEMM: C[N,64] = (H[N,K] @ W[K,64]) * dis[row] ----------------

template <int K>
__global__ __launch_bounds__(256) void gemm_kernel(const float* __restrict__ H,
                                                   const float* __restrict__ W,
                                                   const float* __restrict__ dis,
                                                   float* __restrict__ C, int N) {
  __shared__ float Hs[64][65];
  __shared__ float Ws[K][64];
  const int t = threadIdx.x;
  const int rowBase = blockIdx.x * 64;
  for (int i = t; i < K * 64; i += 256) Ws[i >> 6][i & 63] = W[i];

  const int cg = t & 7, pr = t >> 3;
  const int c0 = cg * 8, r0 = pr * 2;
  float acc0[8] = {0.f, 0.f, 0.f, 0.f, 0.f, 0.f, 0.f, 0.f};
  float acc1[8] = {0.f, 0.f, 0.f, 0.f, 0.f, 0.f, 0.f, 0.f};

  for (int k0 = 0; k0 < K; k0 += 64) {
    __syncthreads();
    for (int i = t; i < 64 * 64; i += 256) {
      int r = i >> 6, kk = i & 63;
      int gr = rowBase + r;
      Hs[r][kk] = (gr < N) ? H[(long)gr * K + k0 + kk] : 0.f;
    }
    __syncthreads();
#pragma unroll 8
    for (int kk = 0; kk < 64; ++kk) {
      float h0 = Hs[r0][kk];
      float h1 = Hs[r0 + 1][kk];
      const float4 w0 = *reinterpret_cast<const float4*>(&Ws[k0 + kk][c0]);
      const float4 w1 = *reinterpret_cast<const float4*>(&Ws[k0 + kk][c0 + 4]);
      acc0[0] += h0 * w0.x; acc0[1] += h0 * w0.y; acc0[2] += h0 * w0.z; acc0[3] += h0 * w0.w;
      acc0[4] += h0 * w1.x; acc0[5] += h0 * w1.y; acc0[6] += h0 * w1.z; acc0[7] += h0 * w1.w;
      acc1[0] += h1 * w0.x; acc1[1] += h1 * w0.y; acc1[2] += h1 * w0.z; acc1[3] += h1 * w0.w;
      acc1[4] += h1 * w1.x; acc1[5] += h1 * w1.y; acc1[6] += h1 * w1.z; acc1[7] += h1 * w1.w;
    }
  }
  int gr0 = rowBase + r0;
  if (gr0 < N) {
    float s = dis[gr0];
    float4* o = reinterpret_cast<float4*>(&C[(long)gr0 * 64 + c0]);
    o[0] = make_float4(acc0[0] * s, acc0[1] * s, acc0[2] * s, acc0[3] * s);
    o[1] = make_float4(acc0[4] * s, acc0[5] * s, acc0[6] * s, acc0[7] * s);
  }
  if (gr0 + 1 < N) {
    float s = dis[gr0 + 1];
    float4* o = reinterpret_cast<float4*>(&C[(long)(gr0 + 1) * 64 + c0]);
    o[0] = make_float4(acc1[0] * s, acc1[1] * s, acc1[2] * s, acc1[3] * s);
    o[1] = make_float4(acc1[4] * s, acc1[5] * s, acc1[6] * s, acc1[7] * s);
  }
}

// ---------------- aggregation (CSR, float4 lanes, 4 edge sub-slots) ------
// Ts rows pre-scaled by dis[src]. out[d] = relu(dis[d]*(Ts[d] + sum Ts[s]) + b)

__global__ __launch_bounds__(256) void aggregate_kernel(
    const float* __restrict__ Ts, const int* __restrict__ csr_src,
    const int* __restrict__ ends, const float* __restrict__ dis,
    const float* __restrict__ bias, float* __restrict__ O, int N) {
  int gid = blockIdx.x * 256 + threadIdx.x;
  int d = gid >> 6;
  if (d >= N) return;
  int lane = threadIdx.x & 63;
  int q = lane >> 4;
  int c = lane & 15;
  int beg = (d == 0) ? 0 : ends[d - 1];
  int m = ends[d] - beg;
  const float4* Tv = (const float4*)Ts;
  const int* sl = csr_src + beg;

  float4 a = make_float4(0.f, 0.f, 0.f, 0.f);
  float4 a2 = make_float4(0.f, 0.f, 0.f, 0.f);
  if (q == 0) a = Tv[(long)d * 16 + c];  // self loop (pre-scaled by dis[d])

  int i = q;
  for (; i + 4 < m; i += 8) {
    int s0 = sl[i];
    int s1 = sl[i + 4];
    float4 r0 = Tv[(long)s0 * 16 + c];
    float4 r1 = Tv[(long)s1 * 16 + c];
    a.x += r0.x; a.y += r0.y; a.z += r0.z; a.w += r0.w;
    a2.x += r1.x; a2.y += r1.y; a2.z += r1.z; a2.w += r1.w;
  }
  if (i < m) {
    float4 r = Tv[(long)sl[i] * 16 + c];
    a.x += r.x; a.y += r.y; a.z += r.z; a.w += r.w;
  }
  a.x += a2.x; a.y += a2.y; a.z += a2.z; a.w += a2.w;

  a.x += __shfl_xor(a.x, 16, 64); a.y += __shfl_xor(a.y, 16, 64);
  a.z += __shfl_xor(a.z, 16, 64); a.w += __shfl_xor(a.w, 16, 64);
  a.x += __shfl_xor(a.x, 32, 64); a.y += __shfl_xor(a.y, 32, 64);
  a.z += __shfl_xor(a.z, 32, 64); a.w += __shfl_xor(a.w, 32, 64);

  if (q == 0) {
    float dd = dis[d];
    float4 b4 = ((const float4*)bias)[c];
    float4 o;
    o.x = fmaxf(a.x * dd + b4.x, 0.f);
    o.y = fmaxf(a.y * dd + b4.y, 0.f);
    o.z = fmaxf(a.z * dd + b4.z, 0.f);
    o.w = fmaxf(a.w * dd + b4.w, 0.f);
    ((float4*)O)[(long)d * 16 + c] = o;
  }
}

// ---------------- pooling ----------------

__global__ void logits_kernel(const float* __restrict__ clo, const float* __restrict__ Wc,
                              const float* __restrict__ bc, float* __restrict__ lb, int N) {
  int i = blockIdx.x * blockDim.x + threadIdx.x;
  if (i >= N) return;
  float s = bc[0];
#pragma unroll
  for (int k = 0; k < 8; ++k) s += clo[(long)i * 8 + k] * Wc[k];
  lb[i] = s;
}

__global__ __launch_bounds__(256) void pool_kernel(
    const float* __restrict__ h3, const float* __restrict__ lb,
    const int* __restrict__ batch, const float* __restrict__ Wa1,
    const float* __restrict__ ba1, const float* __restrict__ Wa2,
    const float* __restrict__ ba2, float* __restrict__ out, int N) {
  __shared__ int sLo, sHi;
  __shared__ float red[256];
  __shared__ float Vs[4][64];
  __shared__ float sse[4];
  __shared__ float gv[64];
  __shared__ float am[16];
  const int g = blockIdx.x;
  const int t = threadIdx.x;
  if (t == 0) {
    int lo = 0, hi = N;
    while (lo < hi) { int mid = (lo + hi) >> 1; if (batch[mid] < g) lo = mid + 1; else hi = mid; }
    sLo = lo;
    lo = 0; hi = N;
    while (lo < hi) { int mid = (lo + hi) >> 1; if (batch[mid] < g + 1) lo = mid + 1; else hi = mid; }
    sHi = lo;
  }
  __syncthreads();
  const int lo = sLo, hi = sHi;

  float lm = -1e30f;
  for (int i = lo + t; i < hi; i += 256) lm = fmaxf(lm, lb[i]);
  red[t] = lm;
  __syncthreads();
  for (int s = 128; s > 0; s >>= 1) {
    if (t < s) red[t] = fmaxf(red[t], red[t + s]);
    __syncthreads();
  }
  const float m = red[0];

  const int f = t & 63, sub = t >> 6;
  float vacc = 0.f, seacc = 0.f;
  for (int i = lo + sub; i < hi; i += 4) {
    float e = expf(lb[i] - m);
    seacc += e;
    vacc += e * h3[(long)i * 64 + f];
  }
  Vs[sub][f] = vacc;
  if (f == 0) sse[sub] = seacc;
  __syncthreads();
  if (t < 64) {
    float se = sse[0] + sse[1] + sse[2] + sse[3];
    float v = Vs[0][f] + Vs[1][f] + Vs[2][f] + Vs[3][f];
    gv[f] = (se > 0.f) ? v / se : 0.f;
  }
  __syncthreads();
  if (t < 16) {
    float a = ba1[t];
#pragma unroll
    for (int k2 = 0; k2 < 64; ++k2) a += gv[k2] * Wa1[k2 * 16 + t];
    am[t] = a > 0.f ? a : 0.f;
  }
  __syncthreads();
  if (t == 0) {
    float o = ba2[0];
#pragma unroll
    for (int j = 0; j < 16; ++j) o += am[j] * Wa2[j];
    out[g] = o;
  }
}

// ---------------- launcher ----------------

extern "C" void kernel_launch(void* const* d_in, const int* in_sizes, int n_in,
                              void* d_out, int out_size, void* d_ws, size_t ws_size,
                              hipStream_t stream) {
  const float* x   = (const float*)d_in[0];
  const float* clo = (const float*)d_in[1];
  const float* W1  = (const float*)d_in[2];
  const float* b1  = (const float*)d_in[3];
  const float* W2  = (const float*)d_in[4];
  const float* b2  = (const float*)d_in[5];
  const float* W3  = (const float*)d_in[6];
  const float* b3  = (const float*)d_in[7];
  const float* Wc  = (const float*)d_in[8];
  const float* bc  = (const float*)d_in[9];
  const float* Wa1 = (const float*)d_in[10];
  const float* ba1 = (const float*)d_in[11];
  const float* Wa2 = (const float*)d_in[12];
  const float* ba2 = (const float*)d_in[13];
  const int* edge  = (const int*)d_in[14];
  const int* batch = (const int*)d_in[15];
  float* out = (float*)d_out;

  const int N = in_sizes[15];        // 100000
  const int E = in_sizes[14] / 2;    // 1600000
  const int G = out_size;            // 256
  const int NBKT = (N + BKT_NODES - 1) >> BKT_SHIFT;  // 782 (<=1024)
  const int NBLK = (E + EPB - 1) / EPB;               // 98 (<=128)

  const int* src = edge;
  const int* dst = edge + E;

  char* p = (char*)d_ws;
  auto alloc = [&](size_t bytes) -> char* {
    char* r = p;
    p += (bytes + 255) & ~(size_t)255;
    return r;
  };
  float* bufA           = (float*)alloc((size_t)N * 64 * sizeof(float));
  float* bufB           = (float*)alloc((size_t)N * 64 * sizeof(float));
  int*   csr_src        = (int*)  alloc((size_t)E * sizeof(int));
  unsigned int* grouped = (unsigned int*)alloc((size_t)E * sizeof(unsigned int));
  int*   hist           = (int*)  alloc((size_t)NBKT * NBLK * sizeof(int));
  int*   ebase          = (int*)  alloc((size_t)NBKT * NBLK * sizeof(int));
  int*   btot           = (int*)  alloc((size_t)NBKT * sizeof(int));
  int*   bbase          = (int*)  alloc((size_t)(NBKT + 1) * sizeof(int));
  int*   ends           = (int*)  alloc((size_t)N * sizeof(int));
  float* dis            = (float*)alloc((size_t)N * sizeof(float));
  float* lb             = (float*)alloc((size_t)N * sizeof(float));
  (void)ws_size; (void)n_in;

  block_hist_kernel<<<NBLK, 256, 0, stream>>>(dst, hist, E, NBKT, NBLK);
  row_scan_kernel<<<NBKT, 128, 0, stream>>>(hist, ebase, btot, NBLK);
  bucket_scan_kernel<<<1, 1024, 0, stream>>>(btot, bbase, E, NBKT);
  group_kernel<<<NBLK, 256, 0, stream>>>(src, dst, bbase, ebase, grouped, E, NBKT, NBLK);
  bucket_build_kernel<<<NBKT, 256, 0, stream>>>(grouped, bbase, csr_src, ends, dis, N);

  const int gN = (N + 255) / 256;
  const int gGemm = (N + 63) / 64;
  const int gAgg  = (N * 64 + 255) / 256;

  gemm_kernel<128><<<gGemm, 256, 0, stream>>>(x, W1, dis, bufA, N);
  aggregate_kernel<<<gAgg, 256, 0, stream>>>(bufA, csr_src, ends, dis, b1, bufB, N);
  gemm_kernel<64><<<gGemm, 256, 0, stream>>>(bufB, W2, dis, bufA, N);
  aggregate_kernel<<<gAgg, 256, 0, stream>>>(bufA, csr_src, ends, dis, b2, bufB, N);
  gemm_kernel<64><<<gGemm, 256, 0, stream>>>(bufB, W3, dis, bufA, N);
  aggregate_kernel<<<gAgg, 256, 0, stream>>>(bufA, csr_src, ends, dis, b3, bufB, N);

  logits_kernel<<<gN, 256, 0, stream>>>(clo, Wc, bc, lb, N);
  pool_kernel<<<G, 256, 0, stream>>>(bufB, lb, batch, Wa1, ba1, Wa2, ba2, out, N);
}

// Round 8
// 479.971 us; speedup vs baseline: 1.3358x; 1.0776x over previous
//
#include <hip/hip_runtime.h>
#include <math.h>

// CSR build via contention-free radix grouping (R7: 517us, structure ~fixed).
// R8 change: GEMM only. R7 gemm evidence: 23% occupancy (49.6KB LDS = 3
// blocks/CU), scalar dword staging, 763GB/s = latency-bound. Fix: 33KB LDS
// (Ws staged in 64-row chunks) -> 4 blocks/CU, float4 staging, float4 LDS
// h-reads.

#define BKT_SHIFT 7
#define BKT_NODES 128
#define BKT_CAP 4096   // LDS staging cap; overflow -> direct-write fallback
#define EPB 16384      // edges per block in hist/group passes (64 iters x 256)

// ---------------- phase A: per-(bucket,block) histogram ----------------
__global__ __launch_bounds__(256) void block_hist_kernel(
    const int* __restrict__ dst, int* __restrict__ hist, int E, int NBKT, int NBLK) {
  __shared__ int lh[1024];  // >= NBKT
  const int t = threadIdx.x;
  const int blk = blockIdx.x;
  for (int k = t; k < NBKT; k += 256) lh[k] = 0;
  __syncthreads();
  const int e0 = blk * EPB;
  const int e1 = min(e0 + EPB, E);
  for (int e = e0 + t; e < e1; e += 256) atomicAdd(&lh[dst[e] >> BKT_SHIFT], 1);
  __syncthreads();
  for (int k = t; k < NBKT; k += 256) hist[k * NBLK + blk] = lh[k];
}

// ---------------- phase B1: per-bucket row scan (grid-parallel) ----------
__global__ __launch_bounds__(128) void row_scan_kernel(
    const int* __restrict__ hist, int* __restrict__ ebase, int* __restrict__ btot,
    int NBLK) {
  __shared__ int sh[128];
  const int k = blockIdx.x;
  const int t = threadIdx.x;
  int v = (t < NBLK) ? hist[(long)k * NBLK + t] : 0;
  sh[t] = v;
  __syncthreads();
  for (int s = 1; s < 128; s <<= 1) {
    int add = (t >= s) ? sh[t - s] : 0;
    __syncthreads();
    sh[t] += add;
    __syncthreads();
  }
  if (t < NBLK) ebase[(long)k * NBLK + t] = sh[t] - v;  // row-local exclusive
  if (t == 127) btot[k] = sh[127];
}

// ---------------- phase B2: scan bucket totals (single block, LDS-only) --
__global__ __launch_bounds__(1024) void bucket_scan_kernel(
    const int* __restrict__ btot, int* __restrict__ bbase, int E, int NBKT) {
  __shared__ int sh[1024];
  const int t = threadIdx.x;
  int v = (t < NBKT) ? btot[t] : 0;
  sh[t] = v;
  __syncthreads();
  for (int s = 1; s < 1024; s <<= 1) {
    int add = (t >= s) ? sh[t - s] : 0;
    __syncthreads();
    sh[t] += add;
    __syncthreads();
  }
  if (t < NBKT) bbase[t] = sh[t] - v;
  if (t == 0) bbase[NBKT] = E;
}

// ---------------- phase C: group edges by bucket (sequential runs) --------
__global__ __launch_bounds__(256) void group_kernel(
    const int* __restrict__ src, const int* __restrict__ dst,
    const int* __restrict__ bbase, const int* __restrict__ ebase,
    unsigned int* __restrict__ grouped, int E, int NBKT, int NBLK) {
  __shared__ int lcur[1024];
  const int t = threadIdx.x;
  const int blk = blockIdx.x;
  for (int k = t; k < NBKT; k += 256)
    lcur[k] = bbase[k] + ebase[(long)k * NBLK + blk];
  __syncthreads();
  const int e0 = blk * EPB;
  const int e1 = min(e0 + EPB, E);
  for (int e = e0 + t; e < e1; e += 256) {
    int d = dst[e];
    int b = d >> BKT_SHIFT;
    int pos = atomicAdd(&lcur[b], 1);
    grouped[pos] = ((unsigned int)(d & (BKT_NODES - 1)) << 17) | (unsigned int)src[e];
  }
}

// ---------------- phase D: per-bucket CSR finalize + ends + dis ----------
__global__ __launch_bounds__(256) void bucket_build_kernel(
    const unsigned int* __restrict__ grouped, const int* __restrict__ bbase,
    int* __restrict__ csr_src, int* __restrict__ ends, float* __restrict__ dis, int N) {
  __shared__ int lcnt[BKT_NODES];
  __shared__ int lsum[BKT_NODES];
  __shared__ int lcur[BKT_NODES];
  __shared__ int stage[BKT_CAP];
  const int b = blockIdx.x;
  const int t = threadIdx.x;
  const int node0 = b << BKT_SHIFT;
  const int nn = min(BKT_NODES, N - node0);
  const int base = bbase[b];
  const int m = bbase[b + 1] - base;

  if (t < BKT_NODES) lcnt[t] = 0;
  __syncthreads();
  for (int i = t; i < m; i += 256) atomicAdd(&lcnt[grouped[base + i] >> 17], 1);
  __syncthreads();
  if (t < BKT_NODES) lsum[t] = lcnt[t];
  __syncthreads();
  for (int s = 1; s < BKT_NODES; s <<= 1) {
    int add = 0;
    if (t < BKT_NODES && t >= s) add = lsum[t - s];
    __syncthreads();
    if (t < BKT_NODES) lsum[t] += add;
    __syncthreads();
  }
  if (t < nn) {
    ends[node0 + t] = base + lsum[t];                      // global inclusive end
    dis[node0 + t] = 1.0f / sqrtf((float)(lcnt[t] + 1));   // +1 self loop
    lcur[t] = lsum[t] - lcnt[t];                           // local exclusive cursor
  }
  __syncthreads();
  if (m <= BKT_CAP) {
    for (int i = t; i < m; i += 256) {
      unsigned int v = grouped[base + i];
      int p = atomicAdd(&lcur[v >> 17], 1);
      stage[p] = (int)(v & 0x1FFFFu);
    }
    __syncthreads();
    for (int i = t; i < m; i += 256) csr_src[base + i] = stage[i];
  } else {  // statistically never; correctness fallback
    for (int i = t; i < m; i += 256) {
      unsigned int v = grouped[base + i];
      int p = atomicAdd(&lcur[v >> 17], 1);
      csr_src[base + p] = (int)(v & 0x1FFFFu);
    }
  }
}

// ---------------- GEMM: C[N,64] = (H[N,K] @ W[K,64]) * dis[row] ----------------
// 64-row tile, 256 thr, thread = 2 rows x 8 cols. LDS 33KB -> 4 blocks/CU.
// Hs rows padded to 68 floats: float4-aligned AND conflict-free (68 = 4 mod 32
// -> 8 rows/wave tile all 32 banks). W staged in 64-row chunks (16KB).

template <int K>
__global__ __launch_bounds__(256) void gemm_kernel(const float* __restrict__ H,
                                                   const float* __restrict__ W,
                                                   const float* __restrict__ dis,
                                                   float* __restrict__ C, int N) {
  __shared__ float Hs[64][68];
  __shared__ float Ws[64][64];
  const int t = threadIdx.x;
  const int rowBase = blockIdx.x * 64;
  const int cg = t & 7, pr = t >> 3;
  const int c0 = cg * 8, r0 = pr * 2;
  float acc0[8] = {0.f, 0.f, 0.f, 0.f, 0.f, 0.f, 0.f, 0.f};
  float acc1[8] = {0.f, 0.f, 0.f, 0.f, 0.f, 0.f, 0.f, 0.f};

  const int sr = t >> 4, sc4 = (t & 15) * 4;  // staging: row, col*4

  for (int k0 = 0; k0 < K; k0 += 64) {
    __syncthreads();
    // stage W chunk [k0..k0+63][0..63] as float4 (1024 float4, 4 per thread)
    {
      const float4* Wv = reinterpret_cast<const float4*>(W + (long)k0 * 64);
#pragma unroll
      for (int i = 0; i < 4; ++i) {
        int idx = t + i * 256;
        *reinterpret_cast<float4*>(&Ws[idx >> 4][(idx & 15) * 4]) = Wv[idx];
      }
    }
    // stage H tile [rowBase..+63][k0..k0+63] as float4 (4 rows per pass)
#pragma unroll
    for (int i = 0; i < 4; ++i) {
      int r = sr + i * 16;
      int gr = rowBase + r;
      float4 v = make_float4(0.f, 0.f, 0.f, 0.f);
      if (gr < N) v = *reinterpret_cast<const float4*>(H + (long)gr * K + k0 + sc4);
      *reinterpret_cast<float4*>(&Hs[r][sc4]) = v;
    }
    __syncthreads();
#pragma unroll 4
    for (int kk = 0; kk < 64; kk += 4) {
      float4 h0 = *reinterpret_cast<const float4*>(&Hs[r0][kk]);
      float4 h1 = *reinterpret_cast<const float4*>(&Hs[r0 + 1][kk]);
#pragma unroll
      for (int j = 0; j < 4; ++j) {
        float hj0 = (&h0.x)[j];
        float hj1 = (&h1.x)[j];
        const float4 w0 = *reinterpret_cast<const float4*>(&Ws[kk + j][c0]);
        const float4 w1 = *reinterpret_cast<const float4*>(&Ws[kk + j][c0 + 4]);
        acc0[0] += hj0 * w0.x; acc0[1] += hj0 * w0.y; acc0[2] += hj0 * w0.z; acc0[3] += hj0 * w0.w;
        acc0[4] += hj0 * w1.x; acc0[5] += hj0 * w1.y; acc0[6] += hj0 * w1.z; acc0[7] += hj0 * w1.w;
        acc1[0] += hj1 * w0.x; acc1[1] += hj1 * w0.y; acc1[2] += hj1 * w0.z; acc1[3] += hj1 * w0.w;
        acc1[4] += hj1 * w1.x; acc1[5] += hj1 * w1.y; acc1[6] += hj1 * w1.z; acc1[7] += hj1 * w1.w;
      }
    }
  }
  int gr0 = rowBase + r0;
  if (gr0 < N) {
    float s = dis[gr0];
    float4* o = reinterpret_cast<float4*>(&C[(long)gr0 * 64 + c0]);
    o[0] = make_float4(acc0[0] * s, acc0[1] * s, acc0[2] * s, acc0[3] * s);
    o[1] = make_float4(acc0[4] * s, acc0[5] * s, acc0[6] * s, acc0[7] * s);
  }
  if (gr0 + 1 < N) {
    float s = dis[gr0 + 1];
    float4* o = reinterpret_cast<float4*>(&C[(long)(gr0 + 1) * 64 + c0]);
    o[0] = make_float4(acc1[0] * s, acc1[1] * s, acc1[2] * s, acc1[3] * s);
    o[1] = make_float4(acc1[4] * s, acc1[5] * s, acc1[6] * s, acc1[7] * s);
  }
}

// ---------------- aggregation (CSR, float4 lanes, 4 edge sub-slots) ------
// Ts rows pre-scaled by dis[src]. out[d] = relu(dis[d]*(Ts[d] + sum Ts[s]) + b)

__global__ __launch_bounds__(256) void aggregate_kernel(
    const float* __restrict__ Ts, const int* __restrict__ csr_src,
    const int* __restrict__ ends, const float* __restrict__ dis,
    const float* __restrict__ bias, float* __restrict__ O, int N) {
  int gid = blockIdx.x * 256 + threadIdx.x;
  int d = gid >> 6;
  if (d >= N) return;
  int lane = threadIdx.x & 63;
  int q = lane >> 4;
  int c = lane & 15;
  int beg = (d == 0) ? 0 : ends[d - 1];
  int m = ends[d] - beg;
  const float4* Tv = (const float4*)Ts;
  const int* sl = csr_src + beg;

  float4 a = make_float4(0.f, 0.f, 0.f, 0.f);
  float4 a2 = make_float4(0.f, 0.f, 0.f, 0.f);
  if (q == 0) a = Tv[(long)d * 16 + c];  // self loop (pre-scaled by dis[d])

  int i = q;
  for (; i + 4 < m; i += 8) {
    int s0 = sl[i];
    int s1 = sl[i + 4];
    float4 r0 = Tv[(long)s0 * 16 + c];
    float4 r1 = Tv[(long)s1 * 16 + c];
    a.x += r0.x; a.y += r0.y; a.z += r0.z; a.w += r0.w;
    a2.x += r1.x; a2.y += r1.y; a2.z += r1.z; a2.w += r1.w;
  }
  if (i < m) {
    float4 r = Tv[(long)sl[i] * 16 + c];
    a.x += r.x; a.y += r.y; a.z += r.z; a.w += r.w;
  }
  a.x += a2.x; a.y += a2.y; a.z += a2.z; a.w += a2.w;

  a.x += __shfl_xor(a.x, 16, 64); a.y += __shfl_xor(a.y, 16, 64);
  a.z += __shfl_xor(a.z, 16, 64); a.w += __shfl_xor(a.w, 16, 64);
  a.x += __shfl_xor(a.x, 32, 64); a.y += __shfl_xor(a.y, 32, 64);
  a.z += __shfl_xor(a.z, 32, 64); a.w += __shfl_xor(a.w, 32, 64);

  if (q == 0) {
    float dd = dis[d];
    float4 b4 = ((const float4*)bias)[c];
    float4 o;
    o.x = fmaxf(a.x * dd + b4.x, 0.f);
    o.y = fmaxf(a.y * dd + b4.y, 0.f);
    o.z = fmaxf(a.z * dd + b4.z, 0.f);
    o.w = fmaxf(a.w * dd + b4.w, 0.f);
    ((float4*)O)[(long)d * 16 + c] = o;
  }
}

// ---------------- pooling ----------------

__global__ void logits_kernel(const float* __restrict__ clo, const float* __restrict__ Wc,
                              const float* __restrict__ bc, float* __restrict__ lb, int N) {
  int i = blockIdx.x * blockDim.x + threadIdx.x;
  if (i >= N) return;
  float s = bc[0];
#pragma unroll
  for (int k = 0; k < 8; ++k) s += clo[(long)i * 8 + k] * Wc[k];
  lb[i] = s;
}

__global__ __launch_bounds__(256) void pool_kernel(
    const float* __restrict__ h3, const float* __restrict__ lb,
    const int* __restrict__ batch, const float* __restrict__ Wa1,
    const float* __restrict__ ba1, const float* __restrict__ Wa2,
    const float* __restrict__ ba2, float* __restrict__ out, int N) {
  __shared__ int sLo, sHi;
  __shared__ float red[256];
  __shared__ float Vs[4][64];
  __shared__ float sse[4];
  __shared__ float gv[64];
  __shared__ float am[16];
  const int g = blockIdx.x;
  const int t = threadIdx.x;
  if (t == 0) {
    int lo = 0, hi = N;
    while (lo < hi) { int mid = (lo + hi) >> 1; if (batch[mid] < g) lo = mid + 1; else hi = mid; }
    sLo = lo;
    lo = 0; hi = N;
    while (lo < hi) { int mid = (lo + hi) >> 1; if (batch[mid] < g + 1) lo = mid + 1; else hi = mid; }
    sHi = lo;
  }
  __syncthreads();
  const int lo = sLo, hi = sHi;

  float lm = -1e30f;
  for (int i = lo + t; i < hi; i += 256) lm = fmaxf(lm, lb[i]);
  red[t] = lm;
  __syncthreads();
  for (int s = 128; s > 0; s >>= 1) {
    if (t < s) red[t] = fmaxf(red[t], red[t + s]);
    __syncthreads();
  }
  const float m = red[0];

  const int f = t & 63, sub = t >> 6;
  float vacc = 0.f, seacc = 0.f;
  for (int i = lo + sub; i < hi; i += 4) {
    float e = expf(lb[i] - m);
    seacc += e;
    vacc += e * h3[(long)i * 64 + f];
  }
  Vs[sub][f] = vacc;
  if (f == 0) sse[sub] = seacc;
  __syncthreads();
  if (t < 64) {
    float se = sse[0] + sse[1] + sse[2] + sse[3];
    float v = Vs[0][f] + Vs[1][f] + Vs[2][f] + Vs[3][f];
    gv[f] = (se > 0.f) ? v / se : 0.f;
  }
  __syncthreads();
  if (t < 16) {
    float a = ba1[t];
#pragma unroll
    for (int k2 = 0; k2 < 64; ++k2) a += gv[k2] * Wa1[k2 * 16 + t];
    am[t] = a > 0.f ? a : 0.f;
  }
  __syncthreads();
  if (t == 0) {
    float o = ba2[0];
#pragma unroll
    for (int j = 0; j < 16; ++j) o += am[j] * Wa2[j];
    out[g] = o;
  }
}

// ---------------- launcher ----------------

extern "C" void kernel_launch(void* const* d_in, const int* in_sizes, int n_in,
                              void* d_out, int out_size, void* d_ws, size_t ws_size,
                              hipStream_t stream) {
  const float* x   = (const float*)d_in[0];
  const float* clo = (const float*)d_in[1];
  const float* W1  = (const float*)d_in[2];
  const float* b1  = (const float*)d_in[3];
  const float* W2  = (const float*)d_in[4];
  const float* b2  = (const float*)d_in[5];
  const float* W3  = (const float*)d_in[6];
  const float* b3  = (const float*)d_in[7];
  const float* Wc  = (const float*)d_in[8];
  const float* bc  = (const float*)d_in[9];
  const float* Wa1 = (const float*)d_in[10];
  const float* ba1 = (const float*)d_in[11];
  const float* Wa2 = (const float*)d_in[12];
  const float* ba2 = (const float*)d_in[13];
  const int* edge  = (const int*)d_in[14];
  const int* batch = (const int*)d_in[15];
  float* out = (float*)d_out;

  const int N = in_sizes[15];        // 100000
  const int E = in_sizes[14] / 2;    // 1600000
  const int G = out_size;            // 256
  const int NBKT = (N + BKT_NODES - 1) >> BKT_SHIFT;  // 782 (<=1024)
  const int NBLK = (E + EPB - 1) / EPB;               // 98 (<=128)

  const int* src = edge;
  const int* dst = edge + E;

  char* p = (char*)d_ws;
  auto alloc = [&](size_t bytes) -> char* {
    char* r = p;
    p += (bytes + 255) & ~(size_t)255;
    return r;
  };
  float* bufA           = (float*)alloc((size_t)N * 64 * sizeof(float));
  float* bufB           = (float*)alloc((size_t)N * 64 * sizeof(float));
  int*   csr_src        = (int*)  alloc((size_t)E * sizeof(int));
  unsigned int* grouped = (unsigned int*)alloc((size_t)E * sizeof(unsigned int));
  int*   hist           = (int*)  alloc((size_t)NBKT * NBLK * sizeof(int));
  int*   ebase          = (int*)  alloc((size_t)NBKT * NBLK * sizeof(int));
  int*   btot           = (int*)  alloc((size_t)NBKT * sizeof(int));
  int*   bbase          = (int*)  alloc((size_t)(NBKT + 1) * sizeof(int));
  int*   ends           = (int*)  alloc((size_t)N * sizeof(int));
  float* dis            = (float*)alloc((size_t)N * sizeof(float));
  float* lb             = (float*)alloc((size_t)N * sizeof(float));
  (void)ws_size; (void)n_in;

  block_hist_kernel<<<NBLK, 256, 0, stream>>>(dst, hist, E, NBKT, NBLK);
  row_scan_kernel<<<NBKT, 128, 0, stream>>>(hist, ebase, btot, NBLK);
  bucket_scan_kernel<<<1, 1024, 0, stream>>>(btot, bbase, E, NBKT);
  group_kernel<<<NBLK, 256, 0, stream>>>(src, dst, bbase, ebase, grouped, E, NBKT, NBLK);
  bucket_build_kernel<<<NBKT, 256, 0, stream>>>(grouped, bbase, csr_src, ends, dis, N);

  const int gN = (N + 255) / 256;
  const int gGemm = (N + 63) / 64;
  const int gAgg  = (N * 64 + 255) / 256;

  gemm_kernel<128><<<gGemm, 256, 0, stream>>>(x, W1, dis, bufA, N);
  aggregate_kernel<<<gAgg, 256, 0, stream>>>(bufA, csr_src, ends, dis, b1, bufB, N);
  gemm_kernel<64><<<gGemm, 256, 0, stream>>>(bufB, W2, dis, bufA, N);
  aggregate_kernel<<<gAgg, 256, 0, stream>>>(bufA, csr_src, ends, dis, b2, bufB, N);
  gemm_kernel<64><<<gGemm, 256, 0, stream>>>(bufB, W3, dis, bufA, N);
  aggregate_kernel<<<gAgg, 256, 0, stream>>>(bufA, csr_src, ends, dis, b3, bufB, N);

  logits_kernel<<<gN, 256, 0, stream>>>(clo, Wc, bc, lb, N);
  pool_kernel<<<G, 256, 0, stream>>>(bufB, lb, batch, Wa1, ba1, Wa2, ba2, out, N);
}

// Round 9
// 471.333 us; speedup vs baseline: 1.3603x; 1.0183x over previous
//
#include <hip/hip_runtime.h>
#include <math.h>

// CSR build via contention-free radix grouping (R7). R8: GEMM 4 blocks/CU +
// float4 staging (480us). R9 change: aggregate only. R8 evidence: agg = 63us,
// FETCH 190MB, 3.5TB/s (44% peak), VALU 27%, occ 74% -> latency-bound on the
// serial index->row chain. Fix: one coalesced index-vector load per wave +
// register __shfl distribution -> 4 independent gather instrs (16 rows) in
// flight, 4 accumulators.

#define BKT_SHIFT 7
#define BKT_NODES 128
#define BKT_CAP 4096   // LDS staging cap; overflow -> direct-write fallback
#define EPB 16384      // edges per block in hist/group passes (64 iters x 256)

// ---------------- phase A: per-(bucket,block) histogram ----------------
__global__ __launch_bounds__(256) void block_hist_kernel(
    const int* __restrict__ dst, int* __restrict__ hist, int E, int NBKT, int NBLK) {
  __shared__ int lh[1024];  // >= NBKT
  const int t = threadIdx.x;
  const int blk = blockIdx.x;
  for (int k = t; k < NBKT; k += 256) lh[k] = 0;
  __syncthreads();
  const int e0 = blk * EPB;
  const int e1 = min(e0 + EPB, E);
  for (int e = e0 + t; e < e1; e += 256) atomicAdd(&lh[dst[e] >> BKT_SHIFT], 1);
  __syncthreads();
  for (int k = t; k < NBKT; k += 256) hist[k * NBLK + blk] = lh[k];
}

// ---------------- phase B1: per-bucket row scan (grid-parallel) ----------
__global__ __launch_bounds__(128) void row_scan_kernel(
    const int* __restrict__ hist, int* __restrict__ ebase, int* __restrict__ btot,
    int NBLK) {
  __shared__ int sh[128];
  const int k = blockIdx.x;
  const int t = threadIdx.x;
  int v = (t < NBLK) ? hist[(long)k * NBLK + t] : 0;
  sh[t] = v;
  __syncthreads();
  for (int s = 1; s < 128; s <<= 1) {
    int add = (t >= s) ? sh[t - s] : 0;
    __syncthreads();
    sh[t] += add;
    __syncthreads();
  }
  if (t < NBLK) ebase[(long)k * NBLK + t] = sh[t] - v;  // row-local exclusive
  if (t == 127) btot[k] = sh[127];
}

// ---------------- phase B2: scan bucket totals (single block, LDS-only) --
__global__ __launch_bounds__(1024) void bucket_scan_kernel(
    const int* __restrict__ btot, int* __restrict__ bbase, int E, int NBKT) {
  __shared__ int sh[1024];
  const int t = threadIdx.x;
  int v = (t < NBKT) ? btot[t] : 0;
  sh[t] = v;
  __syncthreads();
  for (int s = 1; s < 1024; s <<= 1) {
    int add = (t >= s) ? sh[t - s] : 0;
    __syncthreads();
    sh[t] += add;
    __syncthreads();
  }
  if (t < NBKT) bbase[t] = sh[t] - v;
  if (t == 0) bbase[NBKT] = E;
}

// ---------------- phase C: group edges by bucket (sequential runs) --------
__global__ __launch_bounds__(256) void group_kernel(
    const int* __restrict__ src, const int* __restrict__ dst,
    const int* __restrict__ bbase, const int* __restrict__ ebase,
    unsigned int* __restrict__ grouped, int E, int NBKT, int NBLK) {
  __shared__ int lcur[1024];
  const int t = threadIdx.x;
  const int blk = blockIdx.x;
  for (int k = t; k < NBKT; k += 256)
    lcur[k] = bbase[k] + ebase[(long)k * NBLK + blk];
  __syncthreads();
  const int e0 = blk * EPB;
  const int e1 = min(e0 + EPB, E);
  for (int e = e0 + t; e < e1; e += 256) {
    int d = dst[e];
    int b = d >> BKT_SHIFT;
    int pos = atomicAdd(&lcur[b], 1);
    grouped[pos] = ((unsigned int)(d & (BKT_NODES - 1)) << 17) | (unsigned int)src[e];
  }
}

// ---------------- phase D: per-bucket CSR finalize + ends + dis ----------
__global__ __launch_bounds__(256) void bucket_build_kernel(
    const unsigned int* __restrict__ grouped, const int* __restrict__ bbase,
    int* __restrict__ csr_src, int* __restrict__ ends, float* __restrict__ dis, int N) {
  __shared__ int lcnt[BKT_NODES];
  __shared__ int lsum[BKT_NODES];
  __shared__ int lcur[BKT_NODES];
  __shared__ int stage[BKT_CAP];
  const int b = blockIdx.x;
  const int t = threadIdx.x;
  const int node0 = b << BKT_SHIFT;
  const int nn = min(BKT_NODES, N - node0);
  const int base = bbase[b];
  const int m = bbase[b + 1] - base;

  if (t < BKT_NODES) lcnt[t] = 0;
  __syncthreads();
  for (int i = t; i < m; i += 256) atomicAdd(&lcnt[grouped[base + i] >> 17], 1);
  __syncthreads();
  if (t < BKT_NODES) lsum[t] = lcnt[t];
  __syncthreads();
  for (int s = 1; s < BKT_NODES; s <<= 1) {
    int add = 0;
    if (t < BKT_NODES && t >= s) add = lsum[t - s];
    __syncthreads();
    if (t < BKT_NODES) lsum[t] += add;
    __syncthreads();
  }
  if (t < nn) {
    ends[node0 + t] = base + lsum[t];                      // global inclusive end
    dis[node0 + t] = 1.0f / sqrtf((float)(lcnt[t] + 1));   // +1 self loop
    lcur[t] = lsum[t] - lcnt[t];                           // local exclusive cursor
  }
  __syncthreads();
  if (m <= BKT_CAP) {
    for (int i = t; i < m; i += 256) {
      unsigned int v = grouped[base + i];
      int p = atomicAdd(&lcur[v >> 17], 1);
      stage[p] = (int)(v & 0x1FFFFu);
    }
    __syncthreads();
    for (int i = t; i < m; i += 256) csr_src[base + i] = stage[i];
  } else {  // statistically never; correctness fallback
    for (int i = t; i < m; i += 256) {
      unsigned int v = grouped[base + i];
      int p = atomicAdd(&lcur[v >> 17], 1);
      csr_src[base + p] = (int)(v & 0x1FFFFu);
    }
  }
}

// ---------------- GEMM: C[N,64] = (H[N,K] @ W[K,64]) * dis[row] ----------------
// 64-row tile, 256 thr, thread = 2 rows x 8 cols. LDS 33KB -> 4 blocks/CU.

template <int K>
__global__ __launch_bounds__(256) void gemm_kernel(const float* __restrict__ H,
                                                   const float* __restrict__ W,
                                                   const float* __restrict__ dis,
                                                   float* __restrict__ C, int N) {
  __shared__ float Hs[64][68];
  __shared__ float Ws[64][64];
  const int t = threadIdx.x;
  const int rowBase = blockIdx.x * 64;
  const int cg = t & 7, pr = t >> 3;
  const int c0 = cg * 8, r0 = pr * 2;
  float acc0[8] = {0.f, 0.f, 0.f, 0.f, 0.f, 0.f, 0.f, 0.f};
  float acc1[8] = {0.f, 0.f, 0.f, 0.f, 0.f, 0.f, 0.f, 0.f};

  const int sr = t >> 4, sc4 = (t & 15) * 4;  // staging: row, col*4

  for (int k0 = 0; k0 < K; k0 += 64) {
    __syncthreads();
    {
      const float4* Wv = reinterpret_cast<const float4*>(W + (long)k0 * 64);
#pragma unroll
      for (int i = 0; i < 4; ++i) {
        int idx = t + i * 256;
        *reinterpret_cast<float4*>(&Ws[idx >> 4][(idx & 15) * 4]) = Wv[idx];
      }
    }
#pragma unroll
    for (int i = 0; i < 4; ++i) {
      int r = sr + i * 16;
      int gr = rowBase + r;
      float4 v = make_float4(0.f, 0.f, 0.f, 0.f);
      if (gr < N) v = *reinterpret_cast<const float4*>(H + (long)gr * K + k0 + sc4);
      *reinterpret_cast<float4*>(&Hs[r][sc4]) = v;
    }
    __syncthreads();
#pragma unroll 4
    for (int kk = 0; kk < 64; kk += 4) {
      float4 h0 = *reinterpret_cast<const float4*>(&Hs[r0][kk]);
      float4 h1 = *reinterpret_cast<const float4*>(&Hs[r0 + 1][kk]);
#pragma unroll
      for (int j = 0; j < 4; ++j) {
        float hj0 = (&h0.x)[j];
        float hj1 = (&h1.x)[j];
        const float4 w0 = *reinterpret_cast<const float4*>(&Ws[kk + j][c0]);
        const float4 w1 = *reinterpret_cast<const float4*>(&Ws[kk + j][c0 + 4]);
        acc0[0] += hj0 * w0.x; acc0[1] += hj0 * w0.y; acc0[2] += hj0 * w0.z; acc0[3] += hj0 * w0.w;
        acc0[4] += hj0 * w1.x; acc0[5] += hj0 * w1.y; acc0[6] += hj0 * w1.z; acc0[7] += hj0 * w1.w;
        acc1[0] += hj1 * w0.x; acc1[1] += hj1 * w0.y; acc1[2] += hj1 * w0.z; acc1[3] += hj1 * w0.w;
        acc1[4] += hj1 * w1.x; acc1[5] += hj1 * w1.y; acc1[6] += hj1 * w1.z; acc1[7] += hj1 * w1.w;
      }
    }
  }
  int gr0 = rowBase + r0;
  if (gr0 < N) {
    float s = dis[gr0];
    float4* o = reinterpret_cast<float4*>(&C[(long)gr0 * 64 + c0]);
    o[0] = make_float4(acc0[0] * s, acc0[1] * s, acc0[2] * s, acc0[3] * s);
    o[1] = make_float4(acc0[4] * s, acc0[5] * s, acc0[6] * s, acc0[7] * s);
  }
  if (gr0 + 1 < N) {
    float s = dis[gr0 + 1];
    float4* o = reinterpret_cast<float4*>(&C[(long)(gr0 + 1) * 64 + c0]);
    o[0] = make_float4(acc1[0] * s, acc1[1] * s, acc1[2] * s, acc1[3] * s);
    o[1] = make_float4(acc1[4] * s, acc1[5] * s, acc1[6] * s, acc1[7] * s);
  }
}

// ---------------- aggregation (CSR, vector index load + shfl fan-out) ----
// Ts rows pre-scaled by dis[src]. out[d] = relu(dis[d]*(Ts[d] + sum Ts[s]) + b)
// One wave per dst. One coalesced load grabs up to 64 indices; __shfl
// distributes them so 4 gather instructions (16 rows) are in flight at once.

__global__ __launch_bounds__(256) void aggregate_kernel(
    const float* __restrict__ Ts, const int* __restrict__ csr_src,
    const int* __restrict__ ends, const float* __restrict__ dis,
    const float* __restrict__ bias, float* __restrict__ O, int N) {
  int gid = blockIdx.x * 256 + threadIdx.x;
  int d = gid >> 6;
  if (d >= N) return;
  const int lane = threadIdx.x & 63;
  const int q = lane >> 4;
  const int c = lane & 15;
  const int beg = (d == 0) ? 0 : ends[d - 1];
  const int m = ends[d] - beg;  // wave-uniform
  const float4* Tv = (const float4*)Ts;
  const int* sl = csr_src + beg;

  float4 a0 = make_float4(0.f, 0.f, 0.f, 0.f);
  float4 a1 = a0, a2 = a0, a3 = a0;
  if (q == 0) a0 = Tv[(long)d * 16 + c];  // self loop (pre-scaled by dis[d])

  for (int base = 0; base < m; base += 64) {
    const int take = min(m - base, 64);
    int idx = (lane < take) ? sl[base + lane] : 0;  // one coalesced vector load
    for (int j = 0; j < take; j += 16) {
      const int l0 = j + q, l1 = j + 4 + q, l2 = j + 8 + q, l3 = j + 12 + q;
      int s0 = __shfl(idx, l0 & 63, 64);
      int s1 = __shfl(idx, l1 & 63, 64);
      int s2 = __shfl(idx, l2 & 63, 64);
      int s3 = __shfl(idx, l3 & 63, 64);
      float4 r0 = Tv[(long)s0 * 16 + c];
      float4 r1 = Tv[(long)s1 * 16 + c];
      float4 r2 = Tv[(long)s2 * 16 + c];
      float4 r3 = Tv[(long)s3 * 16 + c];
      if (l0 < take) { a0.x += r0.x; a0.y += r0.y; a0.z += r0.z; a0.w += r0.w; }
      if (l1 < take) { a1.x += r1.x; a1.y += r1.y; a1.z += r1.z; a1.w += r1.w; }
      if (l2 < take) { a2.x += r2.x; a2.y += r2.y; a2.z += r2.z; a2.w += r2.w; }
      if (l3 < take) { a3.x += r3.x; a3.y += r3.y; a3.z += r3.z; a3.w += r3.w; }
    }
  }
  a0.x += a1.x; a0.y += a1.y; a0.z += a1.z; a0.w += a1.w;
  a2.x += a3.x; a2.y += a3.y; a2.z += a3.z; a2.w += a3.w;
  a0.x += a2.x; a0.y += a2.y; a0.z += a2.z; a0.w += a2.w;

  a0.x += __shfl_xor(a0.x, 16, 64); a0.y += __shfl_xor(a0.y, 16, 64);
  a0.z += __shfl_xor(a0.z, 16, 64); a0.w += __shfl_xor(a0.w, 16, 64);
  a0.x += __shfl_xor(a0.x, 32, 64); a0.y += __shfl_xor(a0.y, 32, 64);
  a0.z += __shfl_xor(a0.z, 32, 64); a0.w += __shfl_xor(a0.w, 32, 64);

  if (q == 0) {
    float dd = dis[d];
    float4 b4 = ((const float4*)bias)[c];
    float4 o;
    o.x = fmaxf(a0.x * dd + b4.x, 0.f);
    o.y = fmaxf(a0.y * dd + b4.y, 0.f);
    o.z = fmaxf(a0.z * dd + b4.z, 0.f);
    o.w = fmaxf(a0.w * dd + b4.w, 0.f);
    ((float4*)O)[(long)d * 16 + c] = o;
  }
}

// ---------------- pooling ----------------

__global__ void logits_kernel(const float* __restrict__ clo, const float* __restrict__ Wc,
                              const float* __restrict__ bc, float* __restrict__ lb, int N) {
  int i = blockIdx.x * blockDim.x + threadIdx.x;
  if (i >= N) return;
  float s = bc[0];
#pragma unroll
  for (int k = 0; k < 8; ++k) s += clo[(long)i * 8 + k] * Wc[k];
  lb[i] = s;
}

__global__ __launch_bounds__(256) void pool_kernel(
    const float* __restrict__ h3, const float* __restrict__ lb,
    const int* __restrict__ batch, const float* __restrict__ Wa1,
    const float* __restrict__ ba1, const float* __restrict__ Wa2,
    const float* __restrict__ ba2, float* __restrict__ out, int N) {
  __shared__ int sLo, sHi;
  __shared__ float red[256];
  __shared__ float Vs[4][64];
  __shared__ float sse[4];
  __shared__ float gv[64];
  __shared__ float am[16];
  const int g = blockIdx.x;
  const int t = threadIdx.x;
  if (t == 0) {
    int lo = 0, hi = N;
    while (lo < hi) { int mid = (lo + hi) >> 1; if (batch[mid] < g) lo = mid + 1; else hi = mid; }
    sLo = lo;
    lo = 0; hi = N;
    while (lo < hi) { int mid = (lo + hi) >> 1; if (batch[mid] < g + 1) lo = mid + 1; else hi = mid; }
    sHi = lo;
  }
  __syncthreads();
  const int lo = sLo, hi = sHi;

  float lm = -1e30f;
  for (int i = lo + t; i < hi; i += 256) lm = fmaxf(lm, lb[i]);
  red[t] = lm;
  __syncthreads();
  for (int s = 128; s > 0; s >>= 1) {
    if (t < s) red[t] = fmaxf(red[t], red[t + s]);
    __syncthreads();
  }
  const float m = red[0];

  const int f = t & 63, sub = t >> 6;
  float vacc = 0.f, seacc = 0.f;
  for (int i = lo + sub; i < hi; i += 4) {
    float e = expf(lb[i] - m);
    seacc += e;
    vacc += e * h3[(long)i * 64 + f];
  }
  Vs[sub][f] = vacc;
  if (f == 0) sse[sub] = seacc;
  __syncthreads();
  if (t < 64) {
    float se = sse[0] + sse[1] + sse[2] + sse[3];
    float v = Vs[0][f] + Vs[1][f] + Vs[2][f] + Vs[3][f];
    gv[f] = (se > 0.f) ? v / se : 0.f;
  }
  __syncthreads();
  if (t < 16) {
    float a = ba1[t];
#pragma unroll
    for (int k2 = 0; k2 < 64; ++k2) a += gv[k2] * Wa1[k2 * 16 + t];
    am[t] = a > 0.f ? a : 0.f;
  }
  __syncthreads();
  if (t == 0) {
    float o = ba2[0];
#pragma unroll
    for (int j = 0; j < 16; ++j) o += am[j] * Wa2[j];
    out[g] = o;
  }
}

// ---------------- launcher ----------------

extern "C" void kernel_launch(void* const* d_in, const int* in_sizes, int n_in,
                              void* d_out, int out_size, void* d_ws, size_t ws_size,
                              hipStream_t stream) {
  const float* x   = (const float*)d_in[0];
  const float* clo = (const float*)d_in[1];
  const float* W1  = (const float*)d_in[2];
  const float* b1  = (const float*)d_in[3];
  const float* W2  = (const float*)d_in[4];
  const float* b2  = (const float*)d_in[5];
  const float* W3  = (const float*)d_in[6];
  const float* b3  = (const float*)d_in[7];
  const float* Wc  = (const float*)d_in[8];
  const float* bc  = (const float*)d_in[9];
  const float* Wa1 = (const float*)d_in[10];
  const float* ba1 = (const float*)d_in[11];
  const float* Wa2 = (const float*)d_in[12];
  const float* ba2 = (const float*)d_in[13];
  const int* edge  = (const int*)d_in[14];
  const int* batch = (const int*)d_in[15];
  float* out = (float*)d_out;

  const int N = in_sizes[15];        // 100000
  const int E = in_sizes[14] / 2;    // 1600000
  const int G = out_size;            // 256
  const int NBKT = (N + BKT_NODES - 1) >> BKT_SHIFT;  // 782 (<=1024)
  const int NBLK = (E + EPB - 1) / EPB;               // 98 (<=128)

  const int* src = edge;
  const int* dst = edge + E;

  char* p = (char*)d_ws;
  auto alloc = [&](size_t bytes) -> char* {
    char* r = p;
    p += (bytes + 255) & ~(size_t)255;
    return r;
  };
  float* bufA           = (float*)alloc((size_t)N * 64 * sizeof(float));
  float* bufB           = (float*)alloc((size_t)N * 64 * sizeof(float));
  int*   csr_src        = (int*)  alloc((size_t)E * sizeof(int));
  unsigned int* grouped = (unsigned int*)alloc((size_t)E * sizeof(unsigned int));
  int*   hist           = (int*)  alloc((size_t)NBKT * NBLK * sizeof(int));
  int*   ebase          = (int*)  alloc((size_t)NBKT * NBLK * sizeof(int));
  int*   btot           = (int*)  alloc((size_t)NBKT * sizeof(int));
  int*   bbase          = (int*)  alloc((size_t)(NBKT + 1) * sizeof(int));
  int*   ends           = (int*)  alloc((size_t)N * sizeof(int));
  float* dis            = (float*)alloc((size_t)N * sizeof(float));
  float* lb             = (float*)alloc((size_t)N * sizeof(float));
  (void)ws_size; (void)n_in;

  block_hist_kernel<<<NBLK, 256, 0, stream>>>(dst, hist, E, NBKT, NBLK);
  row_scan_kernel<<<NBKT, 128, 0, stream>>>(hist, ebase, btot, NBLK);
  bucket_scan_kernel<<<1, 1024, 0, stream>>>(btot, bbase, E, NBKT);
  group_kernel<<<NBLK, 256, 0, stream>>>(src, dst, bbase, ebase, grouped, E, NBKT, NBLK);
  bucket_build_kernel<<<NBKT, 256, 0, stream>>>(grouped, bbase, csr_src, ends, dis, N);

  const int gN = (N + 255) / 256;
  const int gGemm = (N + 63) / 64;
  const int gAgg  = (N * 64 + 255) / 256;

  gemm_kernel<128><<<gGemm, 256, 0, stream>>>(x, W1, dis, bufA, N);
  aggregate_kernel<<<gAgg, 256, 0, stream>>>(bufA, csr_src, ends, dis, b1, bufB, N);
  gemm_kernel<64><<<gGemm, 256, 0, stream>>>(bufB, W2, dis, bufA, N);
  aggregate_kernel<<<gAgg, 256, 0, stream>>>(bufA, csr_src, ends, dis, b2, bufB, N);
  gemm_kernel<64><<<gGemm, 256, 0, stream>>>(bufB, W3, dis, bufA, N);
  aggregate_kernel<<<gAgg, 256, 0, stream>>>(bufA, csr_src, ends, dis, b3, bufB, N);

  logits_kernel<<<gN, 256, 0, stream>>>(clo, Wc, bc, lb, N);
  pool_kernel<<<G, 256, 0, stream>>>(bufB, lb, batch, Wa1, ba1, Wa2, ba2, out, N);
}

// Round 10
// 429.539 us; speedup vs baseline: 1.4926x; 1.0973x over previous
//
#include <hip/hip_runtime.h>
#include <math.h>

// CSR build via contention-free radix grouping (R7), GEMM 4 blocks/CU (R8),
// aggregate w/ vector index load + shfl fan-out (R9, ~46% peak = near the
// random-gather fabric ceiling). R10 change: hist/group occupancy. R9
// evidence: group_kernel 60.7us @ 2.9% occupancy (98 blocks = 158 idle CUs).
// Fix: EPB 8192 + 1024-thread blocks -> 196 blocks x 16 waves.

#define BKT_SHIFT 7
#define BKT_NODES 128
#define BKT_CAP 4096   // LDS staging cap; overflow -> direct-write fallback
#define EPB 8192       // edges per block in hist/group passes (8 iters x 1024)

// ---------------- phase A: per-(bucket,block) histogram ----------------
__global__ __launch_bounds__(1024) void block_hist_kernel(
    const int* __restrict__ dst, int* __restrict__ hist, int E, int NBKT, int NBLK) {
  __shared__ int lh[1024];  // >= NBKT
  const int t = threadIdx.x;
  const int blk = blockIdx.x;
  for (int k = t; k < NBKT; k += 1024) lh[k] = 0;
  __syncthreads();
  const int e0 = blk * EPB;
  const int e1 = min(e0 + EPB, E);
  for (int e = e0 + t; e < e1; e += 1024) atomicAdd(&lh[dst[e] >> BKT_SHIFT], 1);
  __syncthreads();
  for (int k = t; k < NBKT; k += 1024) hist[k * NBLK + blk] = lh[k];
}

// ---------------- phase B1: per-bucket row scan (grid-parallel) ----------
__global__ __launch_bounds__(256) void row_scan_kernel(
    const int* __restrict__ hist, int* __restrict__ ebase, int* __restrict__ btot,
    int NBLK) {
  __shared__ int sh[256];
  const int k = blockIdx.x;
  const int t = threadIdx.x;
  int v = (t < NBLK) ? hist[(long)k * NBLK + t] : 0;
  sh[t] = v;
  __syncthreads();
  for (int s = 1; s < 256; s <<= 1) {
    int add = (t >= s) ? sh[t - s] : 0;
    __syncthreads();
    sh[t] += add;
    __syncthreads();
  }
  if (t < NBLK) ebase[(long)k * NBLK + t] = sh[t] - v;  // row-local exclusive
  if (t == 255) btot[k] = sh[255];
}

// ---------------- phase B2: scan bucket totals (single block, LDS-only) --
__global__ __launch_bounds__(1024) void bucket_scan_kernel(
    const int* __restrict__ btot, int* __restrict__ bbase, int E, int NBKT) {
  __shared__ int sh[1024];
  const int t = threadIdx.x;
  int v = (t < NBKT) ? btot[t] : 0;
  sh[t] = v;
  __syncthreads();
  for (int s = 1; s < 1024; s <<= 1) {
    int add = (t >= s) ? sh[t - s] : 0;
    __syncthreads();
    sh[t] += add;
    __syncthreads();
  }
  if (t < NBKT) bbase[t] = sh[t] - v;
  if (t == 0) bbase[NBKT] = E;
}

// ---------------- phase C: group edges by bucket (sequential runs) --------
__global__ __launch_bounds__(1024) void group_kernel(
    const int* __restrict__ src, const int* __restrict__ dst,
    const int* __restrict__ bbase, const int* __restrict__ ebase,
    unsigned int* __restrict__ grouped, int E, int NBKT, int NBLK) {
  __shared__ int lcur[1024];
  const int t = threadIdx.x;
  const int blk = blockIdx.x;
  for (int k = t; k < NBKT; k += 1024)
    lcur[k] = bbase[k] + ebase[(long)k * NBLK + blk];
  __syncthreads();
  const int e0 = blk * EPB;
  const int e1 = min(e0 + EPB, E);
  for (int e = e0 + t; e < e1; e += 1024) {
    int d = dst[e];
    int b = d >> BKT_SHIFT;
    int pos = atomicAdd(&lcur[b], 1);
    grouped[pos] = ((unsigned int)(d & (BKT_NODES - 1)) << 17) | (unsigned int)src[e];
  }
}

// ---------------- phase D: per-bucket CSR finalize + ends + dis ----------
__global__ __launch_bounds__(256) void bucket_build_kernel(
    const unsigned int* __restrict__ grouped, const int* __restrict__ bbase,
    int* __restrict__ csr_src, int* __restrict__ ends, float* __restrict__ dis, int N) {
  __shared__ int lcnt[BKT_NODES];
  __shared__ int lsum[BKT_NODES];
  __shared__ int lcur[BKT_NODES];
  __shared__ int stage[BKT_CAP];
  const int b = blockIdx.x;
  const int t = threadIdx.x;
  const int node0 = b << BKT_SHIFT;
  const int nn = min(BKT_NODES, N - node0);
  const int base = bbase[b];
  const int m = bbase[b + 1] - base;

  if (t < BKT_NODES) lcnt[t] = 0;
  __syncthreads();
  for (int i = t; i < m; i += 256) atomicAdd(&lcnt[grouped[base + i] >> 17], 1);
  __syncthreads();
  if (t < BKT_NODES) lsum[t] = lcnt[t];
  __syncthreads();
  for (int s = 1; s < BKT_NODES; s <<= 1) {
    int add = 0;
    if (t < BKT_NODES && t >= s) add = lsum[t - s];
    __syncthreads();
    if (t < BKT_NODES) lsum[t] += add;
    __syncthreads();
  }
  if (t < nn) {
    ends[node0 + t] = base + lsum[t];                      // global inclusive end
    dis[node0 + t] = 1.0f / sqrtf((float)(lcnt[t] + 1));   // +1 self loop
    lcur[t] = lsum[t] - lcnt[t];                           // local exclusive cursor
  }
  __syncthreads();
  if (m <= BKT_CAP) {
    for (int i = t; i < m; i += 256) {
      unsigned int v = grouped[base + i];
      int p = atomicAdd(&lcur[v >> 17], 1);
      stage[p] = (int)(v & 0x1FFFFu);
    }
    __syncthreads();
    for (int i = t; i < m; i += 256) csr_src[base + i] = stage[i];
  } else {  // statistically never; correctness fallback
    for (int i = t; i < m; i += 256) {
      unsigned int v = grouped[base + i];
      int p = atomicAdd(&lcur[v >> 17], 1);
      csr_src[base + p] = (int)(v & 0x1FFFFu);
    }
  }
}

// ---------------- GEMM: C[N,64] = (H[N,K] @ W[K,64]) * dis[row] ----------------
// 64-row tile, 256 thr, thread = 2 rows x 8 cols. LDS 33KB -> 4 blocks/CU.

template <int K>
__global__ __launch_bounds__(256) void gemm_kernel(const float* __restrict__ H,
                                                   const float* __restrict__ W,
                                                   const float* __restrict__ dis,
                                                   float* __restrict__ C, int N) {
  __shared__ float Hs[64][68];
  __shared__ float Ws[64][64];
  const int t = threadIdx.x;
  const int rowBase = blockIdx.x * 64;
  const int cg = t & 7, pr = t >> 3;
  const int c0 = cg * 8, r0 = pr * 2;
  float acc0[8] = {0.f, 0.f, 0.f, 0.f, 0.f, 0.f, 0.f, 0.f};
  float acc1[8] = {0.f, 0.f, 0.f, 0.f, 0.f, 0.f, 0.f, 0.f};

  const int sr = t >> 4, sc4 = (t & 15) * 4;  // staging: row, col*4

  for (int k0 = 0; k0 < K; k0 += 64) {
    __syncthreads();
    {
      const float4* Wv = reinterpret_cast<const float4*>(W + (long)k0 * 64);
#pragma unroll
      for (int i = 0; i < 4; ++i) {
        int idx = t + i * 256;
        *reinterpret_cast<float4*>(&Ws[idx >> 4][(idx & 15) * 4]) = Wv[idx];
      }
    }
#pragma unroll
    for (int i = 0; i < 4; ++i) {
      int r = sr + i * 16;
      int gr = rowBase + r;
      float4 v = make_float4(0.f, 0.f, 0.f, 0.f);
      if (gr < N) v = *reinterpret_cast<const float4*>(H + (long)gr * K + k0 + sc4);
      *reinterpret_cast<float4*>(&Hs[r][sc4]) = v;
    }
    __syncthreads();
#pragma unroll 4
    for (int kk = 0; kk < 64; kk += 4) {
      float4 h0 = *reinterpret_cast<const float4*>(&Hs[r0][kk]);
      float4 h1 = *reinterpret_cast<const float4*>(&Hs[r0 + 1][kk]);
#pragma unroll
      for (int j = 0; j < 4; ++j) {
        float hj0 = (&h0.x)[j];
        float hj1 = (&h1.x)[j];
        const float4 w0 = *reinterpret_cast<const float4*>(&Ws[kk + j][c0]);
        const float4 w1 = *reinterpret_cast<const float4*>(&Ws[kk + j][c0 + 4]);
        acc0[0] += hj0 * w0.x; acc0[1] += hj0 * w0.y; acc0[2] += hj0 * w0.z; acc0[3] += hj0 * w0.w;
        acc0[4] += hj0 * w1.x; acc0[5] += hj0 * w1.y; acc0[6] += hj0 * w1.z; acc0[7] += hj0 * w1.w;
        acc1[0] += hj1 * w0.x; acc1[1] += hj1 * w0.y; acc1[2] += hj1 * w0.z; acc1[3] += hj1 * w0.w;
        acc1[4] += hj1 * w1.x; acc1[5] += hj1 * w1.y; acc1[6] += hj1 * w1.z; acc1[7] += hj1 * w1.w;
      }
    }
  }
  int gr0 = rowBase + r0;
  if (gr0 < N) {
    float s = dis[gr0];
    float4* o = reinterpret_cast<float4*>(&C[(long)gr0 * 64 + c0]);
    o[0] = make_float4(acc0[0] * s, acc0[1] * s, acc0[2] * s, acc0[3] * s);
    o[1] = make_float4(acc0[4] * s, acc0[5] * s, acc0[6] * s, acc0[7] * s);
  }
  if (gr0 + 1 < N) {
    float s = dis[gr0 + 1];
    float4* o = reinterpret_cast<float4*>(&C[(long)(gr0 + 1) * 64 + c0]);
    o[0] = make_float4(acc1[0] * s, acc1[1] * s, acc1[2] * s, acc1[3] * s);
    o[1] = make_float4(acc1[4] * s, acc1[5] * s, acc1[6] * s, acc1[7] * s);
  }
}

// ---------------- aggregation (CSR, vector index load + shfl fan-out) ----
// Ts rows pre-scaled by dis[src]. out[d] = relu(dis[d]*(Ts[d] + sum Ts[s]) + b)

__global__ __launch_bounds__(256) void aggregate_kernel(
    const float* __restrict__ Ts, const int* __restrict__ csr_src,
    const int* __restrict__ ends, const float* __restrict__ dis,
    const float* __restrict__ bias, float* __restrict__ O, int N) {
  int gid = blockIdx.x * 256 + threadIdx.x;
  int d = gid >> 6;
  if (d >= N) return;
  const int lane = threadIdx.x & 63;
  const int q = lane >> 4;
  const int c = lane & 15;
  const int beg = (d == 0) ? 0 : ends[d - 1];
  const int m = ends[d] - beg;  // wave-uniform
  const float4* Tv = (const float4*)Ts;
  const int* sl = csr_src + beg;

  float4 a0 = make_float4(0.f, 0.f, 0.f, 0.f);
  float4 a1 = a0, a2 = a0, a3 = a0;
  if (q == 0) a0 = Tv[(long)d * 16 + c];  // self loop (pre-scaled by dis[d])

  for (int base = 0; base < m; base += 64) {
    const int take = min(m - base, 64);
    int idx = (lane < take) ? sl[base + lane] : 0;  // one coalesced vector load
    for (int j = 0; j < take; j += 16) {
      const int l0 = j + q, l1 = j + 4 + q, l2 = j + 8 + q, l3 = j + 12 + q;
      int s0 = __shfl(idx, l0 & 63, 64);
      int s1 = __shfl(idx, l1 & 63, 64);
      int s2 = __shfl(idx, l2 & 63, 64);
      int s3 = __shfl(idx, l3 & 63, 64);
      float4 r0 = Tv[(long)s0 * 16 + c];
      float4 r1 = Tv[(long)s1 * 16 + c];
      float4 r2 = Tv[(long)s2 * 16 + c];
      float4 r3 = Tv[(long)s3 * 16 + c];
      if (l0 < take) { a0.x += r0.x; a0.y += r0.y; a0.z += r0.z; a0.w += r0.w; }
      if (l1 < take) { a1.x += r1.x; a1.y += r1.y; a1.z += r1.z; a1.w += r1.w; }
      if (l2 < take) { a2.x += r2.x; a2.y += r2.y; a2.z += r2.z; a2.w += r2.w; }
      if (l3 < take) { a3.x += r3.x; a3.y += r3.y; a3.z += r3.z; a3.w += r3.w; }
    }
  }
  a0.x += a1.x; a0.y += a1.y; a0.z += a1.z; a0.w += a1.w;
  a2.x += a3.x; a2.y += a3.y; a2.z += a3.z; a2.w += a3.w;
  a0.x += a2.x; a0.y += a2.y; a0.z += a2.z; a0.w += a2.w;

  a0.x += __shfl_xor(a0.x, 16, 64); a0.y += __shfl_xor(a0.y, 16, 64);
  a0.z += __shfl_xor(a0.z, 16, 64); a0.w += __shfl_xor(a0.w, 16, 64);
  a0.x += __shfl_xor(a0.x, 32, 64); a0.y += __shfl_xor(a0.y, 32, 64);
  a0.z += __shfl_xor(a0.z, 32, 64); a0.w += __shfl_xor(a0.w, 32, 64);

  if (q == 0) {
    float dd = dis[d];
    float4 b4 = ((const float4*)bias)[c];
    float4 o;
    o.x = fmaxf(a0.x * dd + b4.x, 0.f);
    o.y = fmaxf(a0.y * dd + b4.y, 0.f);
    o.z = fmaxf(a0.z * dd + b4.z, 0.f);
    o.w = fmaxf(a0.w * dd + b4.w, 0.f);
    ((float4*)O)[(long)d * 16 + c] = o;
  }
}

// ---------------- pooling ----------------

__global__ void logits_kernel(const float* __restrict__ clo, const float* __restrict__ Wc,
                              const float* __restrict__ bc, float* __restrict__ lb, int N) {
  int i = blockIdx.x * blockDim.x + threadIdx.x;
  if (i >= N) return;
  float s = bc[0];
#pragma unroll
  for (int k = 0; k < 8; ++k) s += clo[(long)i * 8 + k] * Wc[k];
  lb[i] = s;
}

__global__ __launch_bounds__(256) void pool_kernel(
    const float* __restrict__ h3, const float* __restrict__ lb,
    const int* __restrict__ batch, const float* __restrict__ Wa1,
    const float* __restrict__ ba1, const float* __restrict__ Wa2,
    const float* __restrict__ ba2, float* __restrict__ out, int N) {
  __shared__ int sLo, sHi;
  __shared__ float red[256];
  __shared__ float Vs[4][64];
  __shared__ float sse[4];
  __shared__ float gv[64];
  __shared__ float am[16];
  const int g = blockIdx.x;
  const int t = threadIdx.x;
  if (t == 0) {
    int lo = 0, hi = N;
    while (lo < hi) { int mid = (lo + hi) >> 1; if (batch[mid] < g) lo = mid + 1; else hi = mid; }
    sLo = lo;
    lo = 0; hi = N;
    while (lo < hi) { int mid = (lo + hi) >> 1; if (batch[mid] < g + 1) lo = mid + 1; else hi = mid; }
    sHi = lo;
  }
  __syncthreads();
  const int lo = sLo, hi = sHi;

  float lm = -1e30f;
  for (int i = lo + t; i < hi; i += 256) lm = fmaxf(lm, lb[i]);
  red[t] = lm;
  __syncthreads();
  for (int s = 128; s > 0; s >>= 1) {
    if (t < s) red[t] = fmaxf(red[t], red[t + s]);
    __syncthreads();
  }
  const float m = red[0];

  const int f = t & 63, sub = t >> 6;
  float vacc = 0.f, seacc = 0.f;
  for (int i = lo + sub; i < hi; i += 4) {
    float e = expf(lb[i] - m);
    seacc += e;
    vacc += e * h3[(long)i * 64 + f];
  }
  Vs[sub][f] = vacc;
  if (f == 0) sse[sub] = seacc;
  __syncthreads();
  if (t < 64) {
    float se = sse[0] + sse[1] + sse[2] + sse[3];
    float v = Vs[0][f] + Vs[1][f] + Vs[2][f] + Vs[3][f];
    gv[f] = (se > 0.f) ? v / se : 0.f;
  }
  __syncthreads();
  if (t < 16) {
    float a = ba1[t];
#pragma unroll
    for (int k2 = 0; k2 < 64; ++k2) a += gv[k2] * Wa1[k2 * 16 + t];
    am[t] = a > 0.f ? a : 0.f;
  }
  __syncthreads();
  if (t == 0) {
    float o = ba2[0];
#pragma unroll
    for (int j = 0; j < 16; ++j) o += am[j] * Wa2[j];
    out[g] = o;
  }
}

// ---------------- launcher ----------------

extern "C" void kernel_launch(void* const* d_in, const int* in_sizes, int n_in,
                              void* d_out, int out_size, void* d_ws, size_t ws_size,
                              hipStream_t stream) {
  const float* x   = (const float*)d_in[0];
  const float* clo = (const float*)d_in[1];
  const float* W1  = (const float*)d_in[2];
  const float* b1  = (const float*)d_in[3];
  const float* W2  = (const float*)d_in[4];
  const float* b2  = (const float*)d_in[5];
  const float* W3  = (const float*)d_in[6];
  const float* b3  = (const float*)d_in[7];
  const float* Wc  = (const float*)d_in[8];
  const float* bc  = (const float*)d_in[9];
  const float* Wa1 = (const float*)d_in[10];
  const float* ba1 = (const float*)d_in[11];
  const float* Wa2 = (const float*)d_in[12];
  const float* ba2 = (const float*)d_in[13];
  const int* edge  = (const int*)d_in[14];
  const int* batch = (const int*)d_in[15];
  float* out = (float*)d_out;

  const int N = in_sizes[15];        // 100000
  const int E = in_sizes[14] / 2;    // 1600000
  const int G = out_size;            // 256
  const int NBKT = (N + BKT_NODES - 1) >> BKT_SHIFT;  // 782 (<=1024)
  const int NBLK = (E + EPB - 1) / EPB;               // 196 (<=256)

  const int* src = edge;
  const int* dst = edge + E;

  char* p = (char*)d_ws;
  auto alloc = [&](size_t bytes) -> char* {
    char* r = p;
    p += (bytes + 255) & ~(size_t)255;
    return r;
  };
  float* bufA           = (float*)alloc((size_t)N * 64 * sizeof(float));
  float* bufB           = (float*)alloc((size_t)N * 64 * sizeof(float));
  int*   csr_src        = (int*)  alloc((size_t)E * sizeof(int));
  unsigned int* grouped = (unsigned int*)alloc((size_t)E * sizeof(unsigned int));
  int*   hist           = (int*)  alloc((size_t)NBKT * NBLK * sizeof(int));
  int*   ebase          = (int*)  alloc((size_t)NBKT * NBLK * sizeof(int));
  int*   btot           = (int*)  alloc((size_t)NBKT * sizeof(int));
  int*   bbase          = (int*)  alloc((size_t)(NBKT + 1) * sizeof(int));
  int*   ends           = (int*)  alloc((size_t)N * sizeof(int));
  float* dis            = (float*)alloc((size_t)N * sizeof(float));
  float* lb             = (float*)alloc((size_t)N * sizeof(float));
  (void)ws_size; (void)n_in;

  block_hist_kernel<<<NBLK, 1024, 0, stream>>>(dst, hist, E, NBKT, NBLK);
  row_scan_kernel<<<NBKT, 256, 0, stream>>>(hist, ebase, btot, NBLK);
  bucket_scan_kernel<<<1, 1024, 0, stream>>>(btot, bbase, E, NBKT);
  group_kernel<<<NBLK, 1024, 0, stream>>>(src, dst, bbase, ebase, grouped, E, NBKT, NBLK);
  bucket_build_kernel<<<NBKT, 256, 0, stream>>>(grouped, bbase, csr_src, ends, dis, N);

  const int gN = (N + 255) / 256;
  const int gGemm = (N + 63) / 64;
  const int gAgg  = (N * 64 + 255) / 256;

  gemm_kernel<128><<<gGemm, 256, 0, stream>>>(x, W1, dis, bufA, N);
  aggregate_kernel<<<gAgg, 256, 0, stream>>>(bufA, csr_src, ends, dis, b1, bufB, N);
  gemm_kernel<64><<<gGemm, 256, 0, stream>>>(bufB, W2, dis, bufA, N);
  aggregate_kernel<<<gAgg, 256, 0, stream>>>(bufA, csr_src, ends, dis, b2, bufB, N);
  gemm_kernel<64><<<gGemm, 256, 0, stream>>>(bufB, W3, dis, bufA, N);
  aggregate_kernel<<<gAgg, 256, 0, stream>>>(bufA, csr_src, ends, dis, b3, bufB, N);

  logits_kernel<<<gN, 256, 0, stream>>>(clo, Wc, bc, lb, N);
  pool_kernel<<<G, 256, 0, stream>>>(bufB, lb, batch, Wa1, ba1, Wa2, ba2, out, N);
}